// Round 1
// baseline (486.678 us; speedup 1.0000x reference)
//
#include <hip/hip_runtime.h>

#define B_ 8
#define T_ 1024
#define D_ 512
#define H_ 8
#define DK_ 64

typedef __bf16 bf16x8 __attribute__((ext_vector_type(8)));
typedef float f32x4 __attribute__((ext_vector_type(4)));

#define MFMA16(a, b, c) __builtin_amdgcn_mfma_f32_16x16x32_bf16(a, b, c, 0, 0, 0)

__device__ __forceinline__ bf16x8 pack8(float4 a, float4 b) {
  bf16x8 r;
  r[0] = (__bf16)a.x; r[1] = (__bf16)a.y; r[2] = (__bf16)a.z; r[3] = (__bf16)a.w;
  r[4] = (__bf16)b.x; r[5] = (__bf16)b.y; r[6] = (__bf16)b.z; r[7] = (__bf16)b.w;
  return r;
}

// async global->LDS DMA, 16 B per lane; lds base must be wave-uniform.
__device__ __forceinline__ void load_lds16(const void* g, void* l) {
  __builtin_amdgcn_global_load_lds(
      (const __attribute__((address_space(1))) void*)g,
      (__attribute__((address_space(3))) void*)l, 16, 0, 0);
}

// ---------------------------------------------------------------------------
// Prep 1: fp32 -> bf16 convert of the 4 activation inputs, SWIZZLED storage:
// within each 64-elem k-segment, chunk c (8 elem) lands at c ^ (row & 7).
// (Consumed only by the DMA GEMM, which reads raw rows and de-swizzles at
// the LDS fragment read.)
// ---------------------------------------------------------------------------
__global__ __launch_bounds__(256) void cvt_x(const float* __restrict__ q,
                                             const float* __restrict__ k,
                                             const float* __restrict__ v,
                                             const float* __restrict__ p,
                                             __bf16* __restrict__ dst) {
  const float* src = (blockIdx.y == 0) ? q
                   : (blockIdx.y == 1) ? k
                   : (blockIdx.y == 2) ? v : p;
  const size_t e = ((size_t)blockIdx.x * 256 + threadIdx.x) * 8;
  const int row = (int)(e >> 9);
  const int kk = (int)(e & 511);
  const int phys = (kk & ~63) | ((((kk >> 3) & 7) ^ (row & 7)) << 3);
  float4 a = *(const float4*)(src + e);
  float4 b = *(const float4*)(src + e + 4);
  *(bf16x8*)(dst + (size_t)blockIdx.y * 4194304 + (size_t)row * 512 + phys) =
      pack8(a, b);
}

// ---------------------------------------------------------------------------
// Prep 2: convert + transpose the 5 weight matrices to bf16 W^T[n][k],
// swizzled the same way (key = n & 7).
// ---------------------------------------------------------------------------
__global__ __launch_bounds__(256) void cvt_w(const float* __restrict__ w0,
                                             const float* __restrict__ w1,
                                             const float* __restrict__ w2,
                                             const float* __restrict__ w3,
                                             const float* __restrict__ w4,
                                             __bf16* __restrict__ wt) {
  __shared__ float Ts[64][65];
  const float* W = (blockIdx.z == 0) ? w0
                 : (blockIdx.z == 1) ? w1
                 : (blockIdx.z == 2) ? w2
                 : (blockIdx.z == 3) ? w3 : w4;
  const int tid = threadIdx.x;
  const int kt = blockIdx.x * 64, nt = blockIdx.y * 64;
  const int r = tid >> 2, co = (tid & 3) * 16;
#pragma unroll
  for (int q = 0; q < 4; ++q)
    *(float4*)&Ts[r][co + q * 4] =
        *(const float4*)(W + (size_t)(kt + r) * 512 + nt + co + q * 4);
  __syncthreads();
  bf16x8 o0, o1;
#pragma unroll
  for (int q = 0; q < 8; ++q) o0[q] = (__bf16)Ts[co + q][r];
#pragma unroll
  for (int q = 0; q < 8; ++q) o1[q] = (__bf16)Ts[co + 8 + q][r];
  const int key = r & 7;
  __bf16* dst =
      wt + (size_t)blockIdx.z * 262144 + (size_t)(nt + r) * 512 + kt;
  *(bf16x8*)(dst + (((co >> 3) ^ key) << 3)) = o0;
  *(bf16x8*)(dst + ((((co >> 3) + 1) ^ key) << 3)) = o1;
}

// ---------------------------------------------------------------------------
// m97-style DMA GEMM: 128x128 tile, BK=64, 256 thr, wave = 64x64 quadrant.
// A and B staged via global_load_lds(16) into unpadded swizzled LDS tiles;
// fragment reads XOR the chunk index with (l16 & 7) -> uniform bank spread.
// PHASE 0 (grid.z = 0..3): A = Xc[z], scatter epilogues
//   z0 -> quB/qvB (+bq+u / +v), z1 -> kB (+bk), z2 -> v -> LDS-transpose -> vT,
//   z3 -> pB   (all plain layout, consumed by attn's vector loads)
// PHASE 1: A = ctx (swizzled, written by attn), out fp32 row-major (+bo).
// ---------------------------------------------------------------------------
template <int PHASE>
__global__ __launch_bounds__(256, 4) void gemm_dma(
    const __bf16* __restrict__ Xc, const __bf16* __restrict__ ctxA,
    const __bf16* __restrict__ Wt, const float* __restrict__ bq,
    const float* __restrict__ bk, const float* __restrict__ bv,
    const float* __restrict__ bo, const float* __restrict__ u,
    const float* __restrict__ v, __bf16* __restrict__ quB,
    __bf16* __restrict__ qvB, __bf16* __restrict__ kB,
    __bf16* __restrict__ vT, __bf16* __restrict__ pB,
    float* __restrict__ out) {
  __shared__ __bf16 smem[17408];  // As[8192] | Bs[8192]; epilogue: [128][136]
  __bf16* As = smem;
  __bf16* Bs = smem + 8192;
  const int tid = threadIdx.x;
  const int z = blockIdx.z;
  const int wave = tid >> 6, lane = tid & 63, l16 = lane & 15, quad = lane >> 4;
  const int wm = wave & 1, wn = wave >> 1;
  const int m0 = blockIdx.x * 128, n0 = blockIdx.y * 128;

  const __bf16* Ag = PHASE ? ctxA : Xc + (size_t)z * (8192 * 512);
  const __bf16* Bg = Wt + (size_t)(PHASE ? 4 : z) * (512 * 512);

  const int drow = tid >> 3, dch = (tid & 7) * 8;  // DMA lane mapping
  char* ldsA = (char*)As + (tid & 192) * 16;       // wave-uniform base
  char* ldsB = (char*)Bs + (tid & 192) * 16;
  const int keyc = l16 & 7;                        // frag de-swizzle key

  f32x4 acc[4][4];
#pragma unroll
  for (int rb = 0; rb < 4; ++rb)
#pragma unroll
    for (int cb = 0; cb < 4; ++cb) acc[rb][cb] = 0.f;

#pragma unroll 1
  for (int k0 = 0; k0 < 512; k0 += 64) {
    __syncthreads();  // WAR: previous iteration's fragment reads done
#pragma unroll
    for (int c4 = 0; c4 < 4; ++c4) {
      load_lds16(Ag + (size_t)(m0 + c4 * 32 + drow) * 512 + k0 + dch,
                 ldsA + c4 * 4096);
      load_lds16(Bg + (size_t)(n0 + c4 * 32 + drow) * 512 + k0 + dch,
                 ldsB + c4 * 4096);
    }
    __syncthreads();  // DMA drained (vmcnt) before fragment reads
#pragma unroll
    for (int s = 0; s < 2; ++s) {
      const int ph = ((s * 4 + quad) ^ keyc) << 3;
      bf16x8 afr[4], bfr[4];
#pragma unroll
      for (int rb = 0; rb < 4; ++rb)
        afr[rb] = *(const bf16x8*)&As[(wm * 64 + rb * 16 + l16) * 64 + ph];
#pragma unroll
      for (int cb = 0; cb < 4; ++cb)
        bfr[cb] = *(const bf16x8*)&Bs[(wn * 64 + cb * 16 + l16) * 64 + ph];
#pragma unroll
      for (int rb = 0; rb < 4; ++rb)
#pragma unroll
        for (int cb = 0; cb < 4; ++cb)
          acc[rb][cb] = MFMA16(afr[rb], bfr[cb], acc[rb][cb]);
    }
  }

  if (PHASE == 1) {
#pragma unroll
    for (int rb = 0; rb < 4; ++rb)
#pragma unroll
      for (int cb = 0; cb < 4; ++cb) {
        const int col = n0 + wn * 64 + cb * 16 + l16;
        const float bb = bo[col];
#pragma unroll
        for (int r = 0; r < 4; ++r) {
          const int row = m0 + wm * 64 + rb * 16 + quad * 4 + r;
          out[(size_t)row * 512 + col] = acc[rb][cb][r] + bb;
        }
      }
    return;
  }

  if (z == 2) {  // value: bias, transpose in LDS, write vT [B,H,DK,T] (plain)
    __syncthreads();
    __bf16* Tt = smem;  // [128][136]
#pragma unroll
    for (int rb = 0; rb < 4; ++rb)
#pragma unroll
      for (int cb = 0; cb < 4; ++cb) {
        const int cl = wn * 64 + cb * 16 + l16;
        const float bb = bv[n0 + cl];
#pragma unroll
        for (int r = 0; r < 4; ++r) {
          const int rl = wm * 64 + rb * 16 + quad * 4 + r;
          Tt[cl * 136 + rl] = (__bf16)(acc[rb][cb][r] + bb);
        }
      }
    __syncthreads();
    const int r2 = tid >> 1, ch = (tid & 1) * 64;
    const int hh = (n0 + r2) >> 6, dkk = (n0 + r2) & 63;
    const int bI = m0 >> 10, t0 = m0 & 1023;
    __bf16* dst = vT + (((size_t)(bI * H_ + hh)) * DK_ + dkk) * T_ + t0 + ch;
#pragma unroll
    for (int q = 0; q < 8; ++q)
      *(bf16x8*)(dst + q * 8) = *(const bf16x8*)&Tt[r2 * 136 + ch + q * 8];
    return;
  }

#pragma unroll
  for (int rb = 0; rb < 4; ++rb)
#pragma unroll
    for (int cb = 0; cb < 4; ++cb) {
      const int col = n0 + wn * 64 + cb * 16 + l16;
      const float bb = (z == 0) ? bq[col] : (z == 1) ? bk[col] : 0.f;
      const float uu = (z == 0) ? u[col] : 0.f;
      const float vv = (z == 0) ? v[col] : 0.f;
#pragma unroll
      for (int r = 0; r < 4; ++r) {
        const int row = m0 + wm * 64 + rb * 16 + quad * 4 + r;
        const float val = acc[rb][cb][r] + bb;
        const int bI = row >> 10, tt = row & 1023;
        const int hh = col >> 6, dk = col & 63;
        const size_t idx = (((size_t)(bI * H_ + hh)) * T_ + tt) * DK_ + dk;
        if (z == 0) {
          quB[idx] = (__bf16)(val + uu);
          qvB[idx] = (__bf16)(val + vv);
        } else if (z == 1) {
          kB[idx] = (__bf16)val;
        } else {
          pB[idx] = (__bf16)val;
        }
      }
    }
}

// ---------------------------------------------------------------------------
// Fused MFMA attention. Changes this round (occupancy fix):
//  - P band is NO LONGER staged in LDS: the 12 P fragments per wave are
//    loaded directly from global (L2-resident, ~128 KB/bh) into registers at
//    the top of each jt iteration; latency hides under bar+staging+QK^T.
//  - Pa gets its own 64x68 buffer (was aliased into the dropped Pb).
//  - LDS: 9216(Kt)+9216(Vt)+8704(Pa)+8976(Rs) = 36112 B -> 4 blocks/CU
//    co-resident (was 45.8 KB -> 3 resident for 4 blocks of work = tail
//    round at 1/3 throughput; OccupancyPercent showed 25%).
//  - __launch_bounds__(256,4) caps VGPR at 128 so 16 waves/CU fit.
// ctx written SWIZZLED (key row&7) for the DMA out-GEMM.
// ---------------------------------------------------------------------------
__global__ __launch_bounds__(256, 4) void attn_mfma(
    const __bf16* __restrict__ qu, const __bf16* __restrict__ qv,
    const __bf16* __restrict__ kbuf, const __bf16* __restrict__ vT,
    const __bf16* __restrict__ pbuf, __bf16* __restrict__ ctx) {
  constexpr float SCALE = 0.044194173824159216f;  // 1/sqrt(512) (d_model)
  __shared__ __bf16 Kt[64 * 72];   // K[j][k]
  __shared__ __bf16 Vt[64 * 72];   // V^T[d][j]
  __shared__ __bf16 Pa[64 * 68];   // P weights [di][dj] (wave-local rows)
  __shared__ __bf16 Rs[66 * 68];   // pre-shifted pos scores [rr][dj]

  const int tid = threadIdx.x;
  const int wave = tid >> 6, lane = tid & 63, l16 = lane & 15, quad = lane >> 4;
  // XCD swizzle: g&7 = XCD slot; 8 whole (b,h) per XCD, 16 i-tiles contiguous.
  const int g = blockIdx.x;
  const int bhq = (g & 7) * 8 + (g >> 7);
  const int i0 = ((g >> 3) & 15) * 64;
  const size_t bh = (size_t)bhq * T_ * DK_;
  const __bf16* QU = qu + bh;
  const __bf16* QV = qv + bh;
  const __bf16* Kg = kbuf + bh;
  const __bf16* Vg = vT + bh;  // [DK][T]
  const __bf16* Pg = pbuf + bh;

  // A-fragments (pre-biased) held all kernel.
  bf16x8 quA[2], qvw[2], qv4[2];
  {
    const int rw = i0 + wave * 16 + l16;
    const int r4g = i0 + 64 + l16;
    const int r4 = (r4g < T_) ? r4g : T_ - 1;
#pragma unroll
    for (int s = 0; s < 2; ++s) {
      const int ko = s * 32 + quad * 8;
      quA[s] = *(const bf16x8*)&QU[(size_t)rw * DK_ + ko];
      qvw[s] = *(const bf16x8*)&QV[(size_t)rw * DK_ + ko];
      qv4[s] = *(const bf16x8*)&QV[(size_t)r4 * DK_ + ko];
    }
  }

  f32x4 Oacc[4];
#pragma unroll
  for (int cb = 0; cb < 4; ++cb) Oacc[cb] = 0.f;
  float lrun[4];
#pragma unroll
  for (int r = 0; r < 4; ++r) lrun[r] = 0.f;

  const int rbase = wave * 16 + quad * 4;
  const int kr = tid >> 2, kko = (tid & 3) * 16;   // K staging
  const int vd = tid >> 2, vjo = (tid & 3) * 16;   // V staging (from vT)

  bf16x8 kpre[2], vpre[2];
#define LOAD_KV(JT)                                                           \
  {                                                                           \
    const int j0_ = (JT) * 64;                                                \
    const __bf16* ks_ = Kg + (size_t)(j0_ + kr) * DK_ + kko;                  \
    kpre[0] = *(const bf16x8*)ks_;                                            \
    kpre[1] = *(const bf16x8*)(ks_ + 8);                                      \
    const __bf16* vs_ = Vg + (size_t)vd * T_ + j0_ + vjo;                     \
    vpre[0] = *(const bf16x8*)vs_;                                            \
    vpre[1] = *(const bf16x8*)(vs_ + 8);                                      \
  }

  LOAD_KV(0)

#pragma unroll 1
  for (int jt = 0; jt < 16; ++jt) {
    const int j0 = jt * 64;

    // ---- direct P fragment loads (global, L2-hot) for THIS tile ----
    // band row brow maps to global row (cs + brow) mod T.
    int cs = T_ - 65 + j0 - i0;
    if (cs < 0) cs += T_;
    if (cs >= T_) cs -= T_;
    bf16x8 pf[5][2], pfx[2];
#pragma unroll
    for (int c = 0; c < 5; ++c) {
      const int brow = (3 - wave + c) * 16 + l16;
      int prow = cs + brow;
      if (prow >= T_) prow -= T_;
      const __bf16* ps = Pg + (size_t)prow * DK_ + quad * 8;
      pf[c][0] = *(const bf16x8*)ps;
      pf[c][1] = *(const bf16x8*)(ps + 32);
    }
    {
      int prow = cs + wave * 16 + l16;
      if (prow >= T_) prow -= T_;
      const __bf16* ps = Pg + (size_t)prow * DK_ + quad * 8;
      pfx[0] = *(const bf16x8*)ps;
      pfx[1] = *(const bf16x8*)(ps + 32);
    }

    __syncthreads();  // previous iteration's LDS reads complete
    *(bf16x8*)&Kt[kr * 72 + kko] = kpre[0];
    *(bf16x8*)&Kt[kr * 72 + kko + 8] = kpre[1];
    *(bf16x8*)&Vt[vd * 72 + vjo] = vpre[0];
    *(bf16x8*)&Vt[vd * 72 + vjo + 8] = vpre[1];
    __syncthreads();
    if (jt < 15) LOAD_KV(jt + 1)  // overlaps with compute below

    // ---- content scores S = Qu K^T ----
    f32x4 sA[4];
#pragma unroll
    for (int cb = 0; cb < 4; ++cb) sA[cb] = 0.f;
#pragma unroll
    for (int s = 0; s < 2; ++s)
#pragma unroll
      for (int cb = 0; cb < 4; ++cb) {
        bf16x8 kf = *(const bf16x8*)&Kt[(cb * 16 + l16) * 72 + s * 32 + quad * 8];
        sA[cb] = MFMA16(quA[s], kf, sA[cb]);
      }

    // ---- R band GEMM from registers, pre-shifted store ----
#pragma unroll
    for (int c = 0; c < 5; ++c) {
      const int cb = 3 - wave + c;
      f32x4 rc = 0.f;
#pragma unroll
      for (int s = 0; s < 2; ++s) rc = MFMA16(qvw[s], pf[c][s], rc);
      const int col = cb * 16 + l16;
#pragma unroll
      for (int rr = 0; rr < 4; ++rr) {
        const int dj = col + rbase + rr - 64;
        if (dj >= 0 && dj < 64) Rs[(rbase + rr) * 68 + dj] = (__bf16)rc[rr];
      }
    }
    {  // extra row 64 (q row i0+64), cols 0..63, one cb per wave
      f32x4 rc = 0.f;
#pragma unroll
      for (int s = 0; s < 2; ++s) rc = MFMA16(qv4[s], pfx[s], rc);
      if (quad == 0) Rs[64 * 68 + wave * 16 + l16] = (__bf16)rc[0];
    }
    __syncthreads();

    // ---- gather shifted pos, no-max softmax, stash P ----
#pragma unroll
    for (int r = 0; r < 4; ++r) {
#pragma unroll
      for (int cb = 0; cb < 4; ++cb) {
        const int di = rbase + r;
        const int dj = cb * 16 + l16;
        const int ji = (j0 + dj) - (i0 + di);
        float pos = 0.f;
        if (ji != 1) pos = (float)Rs[(di + (ji >= 2 ? 1 : 0)) * 68 + dj];
        const float w_ = __expf((sA[cb][r] + pos) * SCALE);
        lrun[r] += w_;
        Pa[di * 68 + dj] = (__bf16)w_;
      }
    }

    // ---- O += Pa @ V (wave-local rows; in-wave LDS ordering suffices) ----
#pragma unroll
    for (int s = 0; s < 2; ++s) {
      bf16x8 ap = *(const bf16x8*)&Pa[(wave * 16 + l16) * 68 + s * 32 + quad * 8];
#pragma unroll
      for (int cb = 0; cb < 4; ++cb) {
        bf16x8 bv = *(const bf16x8*)&Vt[(cb * 16 + l16) * 72 + s * 32 + quad * 8];
        Oacc[cb] = MFMA16(ap, bv, Oacc[cb]);
      }
    }
  }

  // ---- epilogue: reduce l over 16 lanes, normalize, store ctx SWIZZLED ----
  float inv[4];
#pragma unroll
  for (int r = 0; r < 4; ++r) {
    float L = lrun[r];
    L += __shfl_xor(L, 1);
    L += __shfl_xor(L, 2);
    L += __shfl_xor(L, 4);
    L += __shfl_xor(L, 8);
    inv[r] = 1.f / L;
  }
  const int b = bhq >> 3, h = bhq & 7;
#pragma unroll
  for (int cb = 0; cb < 4; ++cb)
#pragma unroll
    for (int r = 0; r < 4; ++r) {
      const int row = i0 + rbase + r;
      const int chunk = cb * 2 + (l16 >> 3);
      const int col = h * DK_ + ((chunk ^ (row & 7)) << 3) + (l16 & 7);
      ctx[((size_t)(b * T_ + row)) * D_ + col] = (__bf16)(Oacc[cb][r] * inv[r]);
    }
}

// ---------------------------------------------------------------------------
extern "C" void kernel_launch(void* const* d_in, const int* in_sizes, int n_in,
                              void* d_out, int out_size, void* d_ws,
                              size_t ws_size, hipStream_t stream) {
  const float* query = (const float*)d_in[0];
  const float* key   = (const float*)d_in[1];
  const float* value = (const float*)d_in[2];
  const float* pos   = (const float*)d_in[3];
  const float* Wq = (const float*)d_in[4];
  const float* bq = (const float*)d_in[5];
  const float* Wk = (const float*)d_in[6];
  const float* bk = (const float*)d_in[7];
  const float* Wv = (const float*)d_in[8];
  const float* bv = (const float*)d_in[9];
  const float* Wp = (const float*)d_in[10];
  const float* ub = (const float*)d_in[11];
  const float* vbias = (const float*)d_in[12];
  const float* Wo = (const float*)d_in[13];
  const float* bo = (const float*)d_in[14];
  float* out = (float*)d_out;

  // ws: Xc[4] (32MB, swizzled) | quB,qvB,kB,pB,vT (40MB, plain) | Wt (2.5MB)
  // ctx (swizzled) aliases Xc[0] (query slice, consumed before attn writes).
  char* ws = (char*)d_ws;
  const size_t ACT = (size_t)8192 * 512 * 2;  // 8 MB
  __bf16* Xc  = (__bf16*)ws;                  // 4 slices
  __bf16* quB = (__bf16*)(ws + 4 * ACT);
  __bf16* qvB = (__bf16*)(ws + 5 * ACT);
  __bf16* kB  = (__bf16*)(ws + 6 * ACT);
  __bf16* pB  = (__bf16*)(ws + 7 * ACT);
  __bf16* vT  = (__bf16*)(ws + 8 * ACT);
  __bf16* Wt  = (__bf16*)(ws + 9 * ACT);      // 5 x 512 KB
  __bf16* ctx = Xc;                           // alias (query slice)

  cvt_x<<<dim3(2048, 4), 256, 0, stream>>>(query, key, value, pos, Xc);
  cvt_w<<<dim3(8, 8, 5), 256, 0, stream>>>(Wq, Wk, Wv, Wp, Wo, Wt);

  gemm_dma<0><<<dim3(64, 4, 4), 256, 0, stream>>>(
      Xc, nullptr, Wt, bq, bk, bv, bo, ub, vbias, quB, qvB, kB, vT, pB,
      nullptr);

  attn_mfma<<<dim3(1024), 256, 0, stream>>>(quB, qvB, kB, vT, pB, ctx);

  gemm_dma<1><<<dim3(64, 4, 1), 256, 0, stream>>>(
      nullptr, ctx, Wt, bq, bk, bv, bo, ub, vbias, quB, qvB, kB, vT, pB,
      out);
}

// Round 2
// 435.818 us; speedup vs baseline: 1.1167x; 1.1167x over previous
//
#include <hip/hip_runtime.h>

#define B_ 8
#define T_ 1024
#define D_ 512
#define H_ 8
#define DK_ 64

typedef __bf16 bf16x8 __attribute__((ext_vector_type(8)));
typedef float f32x4 __attribute__((ext_vector_type(4)));

#define MFMA16(a, b, c) __builtin_amdgcn_mfma_f32_16x16x32_bf16(a, b, c, 0, 0, 0)

__device__ __forceinline__ bf16x8 pack8(float4 a, float4 b) {
  bf16x8 r;
  r[0] = (__bf16)a.x; r[1] = (__bf16)a.y; r[2] = (__bf16)a.z; r[3] = (__bf16)a.w;
  r[4] = (__bf16)b.x; r[5] = (__bf16)b.y; r[6] = (__bf16)b.z; r[7] = (__bf16)b.w;
  return r;
}

// async global->LDS DMA, 16 B per lane; lds base must be wave-uniform.
__device__ __forceinline__ void load_lds16(const void* g, void* l) {
  __builtin_amdgcn_global_load_lds(
      (const __attribute__((address_space(1))) void*)g,
      (__attribute__((address_space(3))) void*)l, 16, 0, 0);
}

// ---------------------------------------------------------------------------
// Prep 1: fp32 -> bf16 convert of the 4 activation inputs, SWIZZLED storage:
// within each 64-elem k-segment, chunk c (8 elem) lands at c ^ (row & 7).
// (Consumed only by the DMA GEMM, which reads raw rows and de-swizzles at
// the LDS fragment read.)
// ---------------------------------------------------------------------------
__global__ __launch_bounds__(256) void cvt_x(const float* __restrict__ q,
                                             const float* __restrict__ k,
                                             const float* __restrict__ v,
                                             const float* __restrict__ p,
                                             __bf16* __restrict__ dst) {
  const float* src = (blockIdx.y == 0) ? q
                   : (blockIdx.y == 1) ? k
                   : (blockIdx.y == 2) ? v : p;
  const size_t e = ((size_t)blockIdx.x * 256 + threadIdx.x) * 8;
  const int row = (int)(e >> 9);
  const int kk = (int)(e & 511);
  const int phys = (kk & ~63) | ((((kk >> 3) & 7) ^ (row & 7)) << 3);
  float4 a = *(const float4*)(src + e);
  float4 b = *(const float4*)(src + e + 4);
  *(bf16x8*)(dst + (size_t)blockIdx.y * 4194304 + (size_t)row * 512 + phys) =
      pack8(a, b);
}

// ---------------------------------------------------------------------------
// Prep 2: convert + transpose the 5 weight matrices to bf16 W^T[n][k],
// swizzled the same way (key = n & 7).
// ---------------------------------------------------------------------------
__global__ __launch_bounds__(256) void cvt_w(const float* __restrict__ w0,
                                             const float* __restrict__ w1,
                                             const float* __restrict__ w2,
                                             const float* __restrict__ w3,
                                             const float* __restrict__ w4,
                                             __bf16* __restrict__ wt) {
  __shared__ float Ts[64][65];
  const float* W = (blockIdx.z == 0) ? w0
                 : (blockIdx.z == 1) ? w1
                 : (blockIdx.z == 2) ? w2
                 : (blockIdx.z == 3) ? w3 : w4;
  const int tid = threadIdx.x;
  const int kt = blockIdx.x * 64, nt = blockIdx.y * 64;
  const int r = tid >> 2, co = (tid & 3) * 16;
#pragma unroll
  for (int q = 0; q < 4; ++q)
    *(float4*)&Ts[r][co + q * 4] =
        *(const float4*)(W + (size_t)(kt + r) * 512 + nt + co + q * 4);
  __syncthreads();
  bf16x8 o0, o1;
#pragma unroll
  for (int q = 0; q < 8; ++q) o0[q] = (__bf16)Ts[co + q][r];
#pragma unroll
  for (int q = 0; q < 8; ++q) o1[q] = (__bf16)Ts[co + 8 + q][r];
  const int key = r & 7;
  __bf16* dst =
      wt + (size_t)blockIdx.z * 262144 + (size_t)(nt + r) * 512 + kt;
  *(bf16x8*)(dst + (((co >> 3) ^ key) << 3)) = o0;
  *(bf16x8*)(dst + ((((co >> 3) + 1) ^ key) << 3)) = o1;
}

// ---------------------------------------------------------------------------
// m97-style DMA GEMM: 128x128 tile, BK=64, 256 thr, wave = 64x64 quadrant.
// A and B staged via global_load_lds(16) into unpadded swizzled LDS tiles;
// fragment reads XOR the chunk index with (l16 & 7) -> uniform bank spread.
// PHASE 0 (grid.z = 0..3): A = Xc[z], scatter epilogues
//   z0 -> quB/qvB (+bq+u / +v), z1 -> kB (+bk), z2 -> v -> LDS-transpose -> vT,
//   z3 -> pB   (all plain layout, consumed by attn's vector loads)
// PHASE 1: A = ctx (swizzled, written by attn), out fp32 row-major (+bo).
// ---------------------------------------------------------------------------
template <int PHASE>
__global__ __launch_bounds__(256, 4) void gemm_dma(
    const __bf16* __restrict__ Xc, const __bf16* __restrict__ ctxA,
    const __bf16* __restrict__ Wt, const float* __restrict__ bq,
    const float* __restrict__ bk, const float* __restrict__ bv,
    const float* __restrict__ bo, const float* __restrict__ u,
    const float* __restrict__ v, __bf16* __restrict__ quB,
    __bf16* __restrict__ qvB, __bf16* __restrict__ kB,
    __bf16* __restrict__ vT, __bf16* __restrict__ pB,
    float* __restrict__ out) {
  __shared__ __bf16 smem[17408];  // As[8192] | Bs[8192]; epilogue: [128][136]
  __bf16* As = smem;
  __bf16* Bs = smem + 8192;
  const int tid = threadIdx.x;
  const int z = blockIdx.z;
  const int wave = tid >> 6, lane = tid & 63, l16 = lane & 15, quad = lane >> 4;
  const int wm = wave & 1, wn = wave >> 1;
  const int m0 = blockIdx.x * 128, n0 = blockIdx.y * 128;

  const __bf16* Ag = PHASE ? ctxA : Xc + (size_t)z * (8192 * 512);
  const __bf16* Bg = Wt + (size_t)(PHASE ? 4 : z) * (512 * 512);

  const int drow = tid >> 3, dch = (tid & 7) * 8;  // DMA lane mapping
  char* ldsA = (char*)As + (tid & 192) * 16;       // wave-uniform base
  char* ldsB = (char*)Bs + (tid & 192) * 16;
  const int keyc = l16 & 7;                        // frag de-swizzle key

  f32x4 acc[4][4];
#pragma unroll
  for (int rb = 0; rb < 4; ++rb)
#pragma unroll
    for (int cb = 0; cb < 4; ++cb) acc[rb][cb] = 0.f;

#pragma unroll 1
  for (int k0 = 0; k0 < 512; k0 += 64) {
    __syncthreads();  // WAR: previous iteration's fragment reads done
#pragma unroll
    for (int c4 = 0; c4 < 4; ++c4) {
      load_lds16(Ag + (size_t)(m0 + c4 * 32 + drow) * 512 + k0 + dch,
                 ldsA + c4 * 4096);
      load_lds16(Bg + (size_t)(n0 + c4 * 32 + drow) * 512 + k0 + dch,
                 ldsB + c4 * 4096);
    }
    __syncthreads();  // DMA drained (vmcnt) before fragment reads
#pragma unroll
    for (int s = 0; s < 2; ++s) {
      const int ph = ((s * 4 + quad) ^ keyc) << 3;
      bf16x8 afr[4], bfr[4];
#pragma unroll
      for (int rb = 0; rb < 4; ++rb)
        afr[rb] = *(const bf16x8*)&As[(wm * 64 + rb * 16 + l16) * 64 + ph];
#pragma unroll
      for (int cb = 0; cb < 4; ++cb)
        bfr[cb] = *(const bf16x8*)&Bs[(wn * 64 + cb * 16 + l16) * 64 + ph];
#pragma unroll
      for (int rb = 0; rb < 4; ++rb)
#pragma unroll
        for (int cb = 0; cb < 4; ++cb)
          acc[rb][cb] = MFMA16(afr[rb], bfr[cb], acc[rb][cb]);
    }
  }

  if (PHASE == 1) {
#pragma unroll
    for (int rb = 0; rb < 4; ++rb)
#pragma unroll
      for (int cb = 0; cb < 4; ++cb) {
        const int col = n0 + wn * 64 + cb * 16 + l16;
        const float bb = bo[col];
#pragma unroll
        for (int r = 0; r < 4; ++r) {
          const int row = m0 + wm * 64 + rb * 16 + quad * 4 + r;
          out[(size_t)row * 512 + col] = acc[rb][cb][r] + bb;
        }
      }
    return;
  }

  if (z == 2) {  // value: bias, transpose in LDS, write vT [B,H,DK,T] (plain)
    __syncthreads();
    __bf16* Tt = smem;  // [128][136]
#pragma unroll
    for (int rb = 0; rb < 4; ++rb)
#pragma unroll
      for (int cb = 0; cb < 4; ++cb) {
        const int cl = wn * 64 + cb * 16 + l16;
        const float bb = bv[n0 + cl];
#pragma unroll
        for (int r = 0; r < 4; ++r) {
          const int rl = wm * 64 + rb * 16 + quad * 4 + r;
          Tt[cl * 136 + rl] = (__bf16)(acc[rb][cb][r] + bb);
        }
      }
    __syncthreads();
    const int r2 = tid >> 1, ch = (tid & 1) * 64;
    const int hh = (n0 + r2) >> 6, dkk = (n0 + r2) & 63;
    const int bI = m0 >> 10, t0 = m0 & 1023;
    __bf16* dst = vT + (((size_t)(bI * H_ + hh)) * DK_ + dkk) * T_ + t0 + ch;
#pragma unroll
    for (int q = 0; q < 8; ++q)
      *(bf16x8*)(dst + q * 8) = *(const bf16x8*)&Tt[r2 * 136 + ch + q * 8];
    return;
  }

#pragma unroll
  for (int rb = 0; rb < 4; ++rb)
#pragma unroll
    for (int cb = 0; cb < 4; ++cb) {
      const int col = n0 + wn * 64 + cb * 16 + l16;
      const float bb = (z == 0) ? bq[col] : (z == 1) ? bk[col] : 0.f;
      const float uu = (z == 0) ? u[col] : 0.f;
      const float vv = (z == 0) ? v[col] : 0.f;
#pragma unroll
      for (int r = 0; r < 4; ++r) {
        const int row = m0 + wm * 64 + rb * 16 + quad * 4 + r;
        const float val = acc[rb][cb][r] + bb;
        const int bI = row >> 10, tt = row & 1023;
        const int hh = col >> 6, dk = col & 63;
        const size_t idx = (((size_t)(bI * H_ + hh)) * T_ + tt) * DK_ + dk;
        if (z == 0) {
          quB[idx] = (__bf16)(val + uu);
          qvB[idx] = (__bf16)(val + vv);
        } else if (z == 1) {
          kB[idx] = (__bf16)val;
        } else {
          pB[idx] = (__bf16)val;
        }
      }
    }
}

// ---------------------------------------------------------------------------
// Fused MFMA attention. Round-2 occupancy fix (post-mortem of r1's spill):
//  - K and P stay LDS-staged with the register-prefetch pipeline (r0
//    structure — it was fine).
//  - Vt LDS staging is DROPPED: the 8 V fragments (32 VGPR) are loaded
//    directly from global (vT is L2-resident, 128 KB/bh) at the TOP of each
//    iteration and consumed at the END (PV) — full-iteration latency hiding,
//    modest register cost (vs r1's 48-VGPR P prefetch that spilled).
//  - LDS: 9216(Kt)+18432(Pb)+8976(Rs) = 36624 B -> 4 blocks/CU co-resident
//    (r0's 45.8 KB allowed only 3 resident for 4 blocks of work -> 2-round
//    tail, OccupancyPercent 25%).
//  - Per-XCD hot set: K+P+V = 3 MB < 4 MB L2 (r1's 5 MB overflowed).
// ctx written SWIZZLED (key row&7) for the DMA out-GEMM.
// ---------------------------------------------------------------------------
__global__ __launch_bounds__(256, 4) void attn_mfma(
    const __bf16* __restrict__ qu, const __bf16* __restrict__ qv,
    const __bf16* __restrict__ kbuf, const __bf16* __restrict__ vT,
    const __bf16* __restrict__ pbuf, __bf16* __restrict__ ctx) {
  constexpr float SCALE = 0.044194173824159216f;  // 1/sqrt(512) (d_model)
  __shared__ __bf16 Kt[64 * 72];   // K[j][k]
  __shared__ __bf16 Pb[128 * 72];  // P band [o'][k]; Pa aliases this region
  __shared__ __bf16 Rs[66 * 68];   // pre-shifted pos scores [rr][dj]

  const int tid = threadIdx.x;
  const int wave = tid >> 6, lane = tid & 63, l16 = lane & 15, quad = lane >> 4;
  // XCD swizzle: g&7 = XCD slot; 8 whole (b,h) per XCD, 16 i-tiles contiguous.
  const int g = blockIdx.x;
  const int bhq = (g & 7) * 8 + (g >> 7);
  const int i0 = ((g >> 3) & 15) * 64;
  const size_t bh = (size_t)bhq * T_ * DK_;
  const __bf16* QU = qu + bh;
  const __bf16* QV = qv + bh;
  const __bf16* Kg = kbuf + bh;
  const __bf16* Vg = vT + bh;  // [DK][T]
  const __bf16* Pg = pbuf + bh;

  // A-fragments (pre-biased) held all kernel.
  bf16x8 quA[2], qvw[2], qv4[2];
  {
    const int rw = i0 + wave * 16 + l16;
    const int r4g = i0 + 64 + l16;
    const int r4 = (r4g < T_) ? r4g : T_ - 1;
#pragma unroll
    for (int s = 0; s < 2; ++s) {
      const int ko = s * 32 + quad * 8;
      quA[s] = *(const bf16x8*)&QU[(size_t)rw * DK_ + ko];
      qvw[s] = *(const bf16x8*)&QV[(size_t)rw * DK_ + ko];
      qv4[s] = *(const bf16x8*)&QV[(size_t)r4 * DK_ + ko];
    }
  }

  f32x4 Oacc[4];
#pragma unroll
  for (int cb = 0; cb < 4; ++cb) Oacc[cb] = 0.f;
  float lrun[4];
#pragma unroll
  for (int r = 0; r < 4; ++r) lrun[r] = 0.f;

  const int rbase = wave * 16 + quad * 4;
  const int kr = tid >> 2, kko = (tid & 3) * 16;   // K staging
  const int po = tid >> 1, pko = (tid & 1) * 32;   // P staging

  bf16x8 kpre[2], ppre[4];
#define LOAD_KP(JT)                                                           \
  {                                                                           \
    const int j0_ = (JT) * 64;                                                \
    const __bf16* ks_ = Kg + (size_t)(j0_ + kr) * DK_ + kko;                  \
    kpre[0] = *(const bf16x8*)ks_;                                            \
    kpre[1] = *(const bf16x8*)(ks_ + 8);                                      \
    int cs_ = T_ - 65 + j0_ - i0;                                             \
    if (cs_ < 0) cs_ += T_;                                                   \
    if (cs_ >= T_) cs_ -= T_;                                                 \
    int prow_ = cs_ + po;                                                     \
    if (prow_ >= T_) prow_ -= T_;                                             \
    const __bf16* ps_ = Pg + (size_t)prow_ * DK_ + pko;                       \
    ppre[0] = *(const bf16x8*)ps_;                                            \
    ppre[1] = *(const bf16x8*)(ps_ + 8);                                      \
    ppre[2] = *(const bf16x8*)(ps_ + 16);                                     \
    ppre[3] = *(const bf16x8*)(ps_ + 24);                                     \
  }

  LOAD_KP(0)

#pragma unroll 1
  for (int jt = 0; jt < 16; ++jt) {
    const int j0 = jt * 64;

    // ---- V fragments for THIS tile: direct global loads (L2-hot), issued
    // here so QK^T + band GEMM + gather hide their latency; used in PV. ----
    bf16x8 vfr[2][4];
#pragma unroll
    for (int s = 0; s < 2; ++s)
#pragma unroll
      for (int cb = 0; cb < 4; ++cb)
        vfr[s][cb] = *(const bf16x8*)&Vg[(size_t)(cb * 16 + l16) * T_ + j0 +
                                         s * 32 + quad * 8];

    __syncthreads();  // previous iteration's LDS reads complete
    *(bf16x8*)&Kt[kr * 72 + kko] = kpre[0];
    *(bf16x8*)&Kt[kr * 72 + kko + 8] = kpre[1];
    *(bf16x8*)&Pb[po * 72 + pko] = ppre[0];
    *(bf16x8*)&Pb[po * 72 + pko + 8] = ppre[1];
    *(bf16x8*)&Pb[po * 72 + pko + 16] = ppre[2];
    *(bf16x8*)&Pb[po * 72 + pko + 24] = ppre[3];
    __syncthreads();
    if (jt < 15) LOAD_KP(jt + 1)  // overlaps with compute below

    // ---- content scores S = Qu K^T ----
    f32x4 sA[4];
#pragma unroll
    for (int cb = 0; cb < 4; ++cb) sA[cb] = 0.f;
#pragma unroll
    for (int s = 0; s < 2; ++s)
#pragma unroll
      for (int cb = 0; cb < 4; ++cb) {
        bf16x8 kf = *(const bf16x8*)&Kt[(cb * 16 + l16) * 72 + s * 32 + quad * 8];
        sA[cb] = MFMA16(quA[s], kf, sA[cb]);
      }

    // ---- R band GEMM, pre-shifted store (only needed col-blocks) ----
#pragma unroll
    for (int c = 0; c < 5; ++c) {
      const int cb = 3 - wave + c;
      f32x4 rc = 0.f;
#pragma unroll
      for (int s = 0; s < 2; ++s) {
        bf16x8 pf = *(const bf16x8*)&Pb[(cb * 16 + l16) * 72 + s * 32 + quad * 8];
        rc = MFMA16(qvw[s], pf, rc);
      }
      const int col = cb * 16 + l16;
#pragma unroll
      for (int rr = 0; rr < 4; ++rr) {
        const int dj = col + rbase + rr - 64;
        if (dj >= 0 && dj < 64) Rs[(rbase + rr) * 68 + dj] = (__bf16)rc[rr];
      }
    }
    {  // extra row 64 (q row i0+64), cols 0..63, one cb per wave
      const int cb = wave;
      f32x4 rc = 0.f;
#pragma unroll
      for (int s = 0; s < 2; ++s) {
        bf16x8 pf = *(const bf16x8*)&Pb[(cb * 16 + l16) * 72 + s * 32 + quad * 8];
        rc = MFMA16(qv4[s], pf, rc);
      }
      if (quad == 0) Rs[64 * 68 + cb * 16 + l16] = (__bf16)rc[0];
    }
    __syncthreads();

    // ---- gather shifted pos, no-max softmax, stash P (alias of Pb) ----
    __bf16* Pa = Pb;  // safe: Pb fragment reads done before barrier above
#pragma unroll
    for (int r = 0; r < 4; ++r) {
#pragma unroll
      for (int cb = 0; cb < 4; ++cb) {
        const int di = rbase + r;
        const int dj = cb * 16 + l16;
        const int ji = (j0 + dj) - (i0 + di);
        float pos = 0.f;
        if (ji != 1) pos = (float)Rs[(di + (ji >= 2 ? 1 : 0)) * 68 + dj];
        const float w_ = __expf((sA[cb][r] + pos) * SCALE);
        lrun[r] += w_;
        Pa[di * 68 + dj] = (__bf16)w_;
      }
    }

    // ---- O += Pa @ V (wave-local rows; V fragments from registers) ----
#pragma unroll
    for (int s = 0; s < 2; ++s) {
      bf16x8 ap = *(const bf16x8*)&Pa[(wave * 16 + l16) * 68 + s * 32 + quad * 8];
#pragma unroll
      for (int cb = 0; cb < 4; ++cb)
        Oacc[cb] = MFMA16(ap, vfr[s][cb], Oacc[cb]);
    }
  }

  // ---- epilogue: reduce l over 16 lanes, normalize, store ctx SWIZZLED ----
  float inv[4];
#pragma unroll
  for (int r = 0; r < 4; ++r) {
    float L = lrun[r];
    L += __shfl_xor(L, 1);
    L += __shfl_xor(L, 2);
    L += __shfl_xor(L, 4);
    L += __shfl_xor(L, 8);
    inv[r] = 1.f / L;
  }
  const int b = bhq >> 3, h = bhq & 7;
#pragma unroll
  for (int cb = 0; cb < 4; ++cb)
#pragma unroll
    for (int r = 0; r < 4; ++r) {
      const int row = i0 + rbase + r;
      const int chunk = cb * 2 + (l16 >> 3);
      const int col = h * DK_ + ((chunk ^ (row & 7)) << 3) + (l16 & 7);
      ctx[((size_t)(b * T_ + row)) * D_ + col] = (__bf16)(Oacc[cb][r] * inv[r]);
    }
}

// ---------------------------------------------------------------------------
extern "C" void kernel_launch(void* const* d_in, const int* in_sizes, int n_in,
                              void* d_out, int out_size, void* d_ws,
                              size_t ws_size, hipStream_t stream) {
  const float* query = (const float*)d_in[0];
  const float* key   = (const float*)d_in[1];
  const float* value = (const float*)d_in[2];
  const float* pos   = (const float*)d_in[3];
  const float* Wq = (const float*)d_in[4];
  const float* bq = (const float*)d_in[5];
  const float* Wk = (const float*)d_in[6];
  const float* bk = (const float*)d_in[7];
  const float* Wv = (const float*)d_in[8];
  const float* bv = (const float*)d_in[9];
  const float* Wp = (const float*)d_in[10];
  const float* ub = (const float*)d_in[11];
  const float* vbias = (const float*)d_in[12];
  const float* Wo = (const float*)d_in[13];
  const float* bo = (const float*)d_in[14];
  float* out = (float*)d_out;

  // ws: Xc[4] (32MB, swizzled) | quB,qvB,kB,pB,vT (40MB, plain) | Wt (2.5MB)
  // ctx (swizzled) aliases Xc[0] (query slice, consumed before attn writes).
  char* ws = (char*)d_ws;
  const size_t ACT = (size_t)8192 * 512 * 2;  // 8 MB
  __bf16* Xc  = (__bf16*)ws;                  // 4 slices
  __bf16* quB = (__bf16*)(ws + 4 * ACT);
  __bf16* qvB = (__bf16*)(ws + 5 * ACT);
  __bf16* kB  = (__bf16*)(ws + 6 * ACT);
  __bf16* pB  = (__bf16*)(ws + 7 * ACT);
  __bf16* vT  = (__bf16*)(ws + 8 * ACT);
  __bf16* Wt  = (__bf16*)(ws + 9 * ACT);      // 5 x 512 KB
  __bf16* ctx = Xc;                           // alias (query slice)

  cvt_x<<<dim3(2048, 4), 256, 0, stream>>>(query, key, value, pos, Xc);
  cvt_w<<<dim3(8, 8, 5), 256, 0, stream>>>(Wq, Wk, Wv, Wp, Wo, Wt);

  gemm_dma<0><<<dim3(64, 4, 4), 256, 0, stream>>>(
      Xc, nullptr, Wt, bq, bk, bv, bo, ub, vbias, quB, qvB, kB, vT, pB,
      nullptr);

  attn_mfma<<<dim3(1024), 256, 0, stream>>>(quB, qvB, kB, vT, pB, ctx);

  gemm_dma<1><<<dim3(64, 4, 1), 256, 0, stream>>>(
      nullptr, ctx, Wt, bq, bk, bv, bo, ub, vbias, quB, qvB, kB, vT, pB,
      out);
}

// Round 3
// 277.663 us; speedup vs baseline: 1.7528x; 1.5696x over previous
//
#include <hip/hip_runtime.h>

#define B_ 8
#define T_ 1024
#define D_ 512
#define H_ 8
#define DK_ 64

typedef __bf16 bf16x8 __attribute__((ext_vector_type(8)));
typedef float f32x4 __attribute__((ext_vector_type(4)));

#define MFMA16(a, b, c) __builtin_amdgcn_mfma_f32_16x16x32_bf16(a, b, c, 0, 0, 0)

__device__ __forceinline__ bf16x8 pack8(float4 a, float4 b) {
  bf16x8 r;
  r[0] = (__bf16)a.x; r[1] = (__bf16)a.y; r[2] = (__bf16)a.z; r[3] = (__bf16)a.w;
  r[4] = (__bf16)b.x; r[5] = (__bf16)b.y; r[6] = (__bf16)b.z; r[7] = (__bf16)b.w;
  return r;
}

// async global->LDS DMA, 16 B per lane; lds base must be wave-uniform.
__device__ __forceinline__ void load_lds16(const void* g, void* l) {
  __builtin_amdgcn_global_load_lds(
      (const __attribute__((address_space(1))) void*)g,
      (__attribute__((address_space(3))) void*)l, 16, 0, 0);
}

// ---------------------------------------------------------------------------
// Prep 1: fp32 -> bf16 convert of the 4 activation inputs, SWIZZLED storage:
// within each 64-elem k-segment, chunk c (8 elem) lands at c ^ (row & 7).
// (Consumed only by the DMA GEMM, which reads raw rows and de-swizzles at
// the LDS fragment read.)
// ---------------------------------------------------------------------------
__global__ __launch_bounds__(256) void cvt_x(const float* __restrict__ q,
                                             const float* __restrict__ k,
                                             const float* __restrict__ v,
                                             const float* __restrict__ p,
                                             __bf16* __restrict__ dst) {
  const float* src = (blockIdx.y == 0) ? q
                   : (blockIdx.y == 1) ? k
                   : (blockIdx.y == 2) ? v : p;
  const size_t e = ((size_t)blockIdx.x * 256 + threadIdx.x) * 8;
  const int row = (int)(e >> 9);
  const int kk = (int)(e & 511);
  const int phys = (kk & ~63) | ((((kk >> 3) & 7) ^ (row & 7)) << 3);
  float4 a = *(const float4*)(src + e);
  float4 b = *(const float4*)(src + e + 4);
  *(bf16x8*)(dst + (size_t)blockIdx.y * 4194304 + (size_t)row * 512 + phys) =
      pack8(a, b);
}

// ---------------------------------------------------------------------------
// Prep 2: convert + transpose the 5 weight matrices to bf16 W^T[n][k],
// swizzled the same way (key = n & 7).
// ---------------------------------------------------------------------------
__global__ __launch_bounds__(256) void cvt_w(const float* __restrict__ w0,
                                             const float* __restrict__ w1,
                                             const float* __restrict__ w2,
                                             const float* __restrict__ w3,
                                             const float* __restrict__ w4,
                                             __bf16* __restrict__ wt) {
  __shared__ float Ts[64][65];
  const float* W = (blockIdx.z == 0) ? w0
                 : (blockIdx.z == 1) ? w1
                 : (blockIdx.z == 2) ? w2
                 : (blockIdx.z == 3) ? w3 : w4;
  const int tid = threadIdx.x;
  const int kt = blockIdx.x * 64, nt = blockIdx.y * 64;
  const int r = tid >> 2, co = (tid & 3) * 16;
#pragma unroll
  for (int q = 0; q < 4; ++q)
    *(float4*)&Ts[r][co + q * 4] =
        *(const float4*)(W + (size_t)(kt + r) * 512 + nt + co + q * 4);
  __syncthreads();
  bf16x8 o0, o1;
#pragma unroll
  for (int q = 0; q < 8; ++q) o0[q] = (__bf16)Ts[co + q][r];
#pragma unroll
  for (int q = 0; q < 8; ++q) o1[q] = (__bf16)Ts[co + 8 + q][r];
  const int key = r & 7;
  __bf16* dst =
      wt + (size_t)blockIdx.z * 262144 + (size_t)(nt + r) * 512 + kt;
  *(bf16x8*)(dst + (((co >> 3) ^ key) << 3)) = o0;
  *(bf16x8*)(dst + ((((co >> 3) + 1) ^ key) << 3)) = o1;
}

// ---------------------------------------------------------------------------
// m97-style DMA GEMM: 128x128 tile, BK=64, 256 thr, wave = 64x64 quadrant.
// A and B staged via global_load_lds(16) into unpadded swizzled LDS tiles;
// fragment reads XOR the chunk index with (l16 & 7) -> uniform bank spread.
// PHASE 0 (grid.z = 0..3): A = Xc[z], scatter epilogues
//   z0 -> quB/qvB (+bq+u / +v), z1 -> kB (+bk), z2 -> v -> LDS-transpose -> vT,
//   z3 -> pB   (all plain layout, consumed by attn's vector loads)
// PHASE 1: A = ctx (swizzled, written by attn), out fp32 row-major (+bo).
// ---------------------------------------------------------------------------
template <int PHASE>
__global__ __launch_bounds__(256, 4) void gemm_dma(
    const __bf16* __restrict__ Xc, const __bf16* __restrict__ ctxA,
    const __bf16* __restrict__ Wt, const float* __restrict__ bq,
    const float* __restrict__ bk, const float* __restrict__ bv,
    const float* __restrict__ bo, const float* __restrict__ u,
    const float* __restrict__ v, __bf16* __restrict__ quB,
    __bf16* __restrict__ qvB, __bf16* __restrict__ kB,
    __bf16* __restrict__ vT, __bf16* __restrict__ pB,
    float* __restrict__ out) {
  __shared__ __bf16 smem[17408];  // As[8192] | Bs[8192]; epilogue: [128][136]
  __bf16* As = smem;
  __bf16* Bs = smem + 8192;
  const int tid = threadIdx.x;
  const int z = blockIdx.z;
  const int wave = tid >> 6, lane = tid & 63, l16 = lane & 15, quad = lane >> 4;
  const int wm = wave & 1, wn = wave >> 1;
  const int m0 = blockIdx.x * 128, n0 = blockIdx.y * 128;

  const __bf16* Ag = PHASE ? ctxA : Xc + (size_t)z * (8192 * 512);
  const __bf16* Bg = Wt + (size_t)(PHASE ? 4 : z) * (512 * 512);

  const int drow = tid >> 3, dch = (tid & 7) * 8;  // DMA lane mapping
  char* ldsA = (char*)As + (tid & 192) * 16;       // wave-uniform base
  char* ldsB = (char*)Bs + (tid & 192) * 16;
  const int keyc = l16 & 7;                        // frag de-swizzle key

  f32x4 acc[4][4];
#pragma unroll
  for (int rb = 0; rb < 4; ++rb)
#pragma unroll
    for (int cb = 0; cb < 4; ++cb) acc[rb][cb] = 0.f;

#pragma unroll 1
  for (int k0 = 0; k0 < 512; k0 += 64) {
    __syncthreads();  // WAR: previous iteration's fragment reads done
#pragma unroll
    for (int c4 = 0; c4 < 4; ++c4) {
      load_lds16(Ag + (size_t)(m0 + c4 * 32 + drow) * 512 + k0 + dch,
                 ldsA + c4 * 4096);
      load_lds16(Bg + (size_t)(n0 + c4 * 32 + drow) * 512 + k0 + dch,
                 ldsB + c4 * 4096);
    }
    __syncthreads();  // DMA drained (vmcnt) before fragment reads
#pragma unroll
    for (int s = 0; s < 2; ++s) {
      const int ph = ((s * 4 + quad) ^ keyc) << 3;
      bf16x8 afr[4], bfr[4];
#pragma unroll
      for (int rb = 0; rb < 4; ++rb)
        afr[rb] = *(const bf16x8*)&As[(wm * 64 + rb * 16 + l16) * 64 + ph];
#pragma unroll
      for (int cb = 0; cb < 4; ++cb)
        bfr[cb] = *(const bf16x8*)&Bs[(wn * 64 + cb * 16 + l16) * 64 + ph];
#pragma unroll
      for (int rb = 0; rb < 4; ++rb)
#pragma unroll
        for (int cb = 0; cb < 4; ++cb)
          acc[rb][cb] = MFMA16(afr[rb], bfr[cb], acc[rb][cb]);
    }
  }

  if (PHASE == 1) {
#pragma unroll
    for (int rb = 0; rb < 4; ++rb)
#pragma unroll
      for (int cb = 0; cb < 4; ++cb) {
        const int col = n0 + wn * 64 + cb * 16 + l16;
        const float bb = bo[col];
#pragma unroll
        for (int r = 0; r < 4; ++r) {
          const int row = m0 + wm * 64 + rb * 16 + quad * 4 + r;
          out[(size_t)row * 512 + col] = acc[rb][cb][r] + bb;
        }
      }
    return;
  }

  if (z == 2) {  // value: bias, transpose in LDS, write vT [B,H,DK,T] (plain)
    __syncthreads();
    __bf16* Tt = smem;  // [128][136]
#pragma unroll
    for (int rb = 0; rb < 4; ++rb)
#pragma unroll
      for (int cb = 0; cb < 4; ++cb) {
        const int cl = wn * 64 + cb * 16 + l16;
        const float bb = bv[n0 + cl];
#pragma unroll
        for (int r = 0; r < 4; ++r) {
          const int rl = wm * 64 + rb * 16 + quad * 4 + r;
          Tt[cl * 136 + rl] = (__bf16)(acc[rb][cb][r] + bb);
        }
      }
    __syncthreads();
    const int r2 = tid >> 1, ch = (tid & 1) * 64;
    const int hh = (n0 + r2) >> 6, dkk = (n0 + r2) & 63;
    const int bI = m0 >> 10, t0 = m0 & 1023;
    __bf16* dst = vT + (((size_t)(bI * H_ + hh)) * DK_ + dkk) * T_ + t0 + ch;
#pragma unroll
    for (int q = 0; q < 8; ++q)
      *(bf16x8*)(dst + q * 8) = *(const bf16x8*)&Tt[r2 * 136 + ch + q * 8];
    return;
  }

#pragma unroll
  for (int rb = 0; rb < 4; ++rb)
#pragma unroll
    for (int cb = 0; cb < 4; ++cb) {
      const int col = n0 + wn * 64 + cb * 16 + l16;
      const float bb = (z == 0) ? bq[col] : (z == 1) ? bk[col] : 0.f;
      const float uu = (z == 0) ? u[col] : 0.f;
      const float vv = (z == 0) ? v[col] : 0.f;
#pragma unroll
      for (int r = 0; r < 4; ++r) {
        const int row = m0 + wm * 64 + rb * 16 + quad * 4 + r;
        const float val = acc[rb][cb][r] + bb;
        const int bI = row >> 10, tt = row & 1023;
        const int hh = col >> 6, dk = col & 63;
        const size_t idx = (((size_t)(bI * H_ + hh)) * T_ + tt) * DK_ + dk;
        if (z == 0) {
          quB[idx] = (__bf16)(val + uu);
          qvB[idx] = (__bf16)(val + vv);
        } else if (z == 1) {
          kB[idx] = (__bf16)val;
        } else {
          pB[idx] = (__bf16)val;
        }
      }
    }
}

// ---------------------------------------------------------------------------
// Fused MFMA attention — Round-3 occupancy fix, zero register-pressure delta:
// EXACT r0 body (Vt + Pb both LDS-staged, 84 VGPR, launch_bounds(256,3))
// with Rs ALIASED into Kt. Kt is only read in the QK^T phase; a new barrier
// between QK^T and the band GEMM makes the lifetimes disjoint (band writes
// Rs over the Kt region; next iteration's top barrier covers restaging).
// LDS: 9216(Kt|Rs) + 9216(Vt) + 18432(Pb) = 36864 B -> 4 blocks/CU
// co-resident (r0's 45.8 KB allowed only 3 for 4 blocks of work -> 25% occ).
// Registers are NOT the binding constraint (84 regs -> 6 blocks/CU), so no
// launch-bounds tightening -> no r1/r2 spill.
// ctx written SWIZZLED (key row&7) for the DMA out-GEMM.
// ---------------------------------------------------------------------------
__global__ __launch_bounds__(256, 3) void attn_mfma(
    const __bf16* __restrict__ qu, const __bf16* __restrict__ qv,
    const __bf16* __restrict__ kbuf, const __bf16* __restrict__ vT,
    const __bf16* __restrict__ pbuf, __bf16* __restrict__ ctx) {
  constexpr float SCALE = 0.044194173824159216f;  // 1/sqrt(512) (d_model)
  __shared__ __bf16 Kt[64 * 72];   // K[j][k]; after QK^T phase: aliased as Rs
  __shared__ __bf16 Vt[64 * 72];   // V^T[d][j]
  __shared__ __bf16 Pb[128 * 72];  // P band [o'][k]; Pa aliases this region
  __bf16* Rs = Kt;  // pre-shifted pos scores [rr][dj], stride 68 (8976 B fit)

  const int tid = threadIdx.x;
  const int wave = tid >> 6, lane = tid & 63, l16 = lane & 15, quad = lane >> 4;
  // XCD swizzle: g&7 = XCD slot; 8 whole (b,h) per XCD, 16 i-tiles contiguous.
  const int g = blockIdx.x;
  const int bhq = (g & 7) * 8 + (g >> 7);
  const int i0 = ((g >> 3) & 15) * 64;
  const size_t bh = (size_t)bhq * T_ * DK_;
  const __bf16* QU = qu + bh;
  const __bf16* QV = qv + bh;
  const __bf16* Kg = kbuf + bh;
  const __bf16* Vg = vT + bh;  // [DK][T]
  const __bf16* Pg = pbuf + bh;

  // A-fragments (pre-biased) held all kernel.
  bf16x8 quA[2], qvw[2], qv4[2];
  {
    const int rw = i0 + wave * 16 + l16;
    const int r4g = i0 + 64 + l16;
    const int r4 = (r4g < T_) ? r4g : T_ - 1;
#pragma unroll
    for (int s = 0; s < 2; ++s) {
      const int ko = s * 32 + quad * 8;
      quA[s] = *(const bf16x8*)&QU[(size_t)rw * DK_ + ko];
      qvw[s] = *(const bf16x8*)&QV[(size_t)rw * DK_ + ko];
      qv4[s] = *(const bf16x8*)&QV[(size_t)r4 * DK_ + ko];
    }
  }

  f32x4 Oacc[4];
#pragma unroll
  for (int cb = 0; cb < 4; ++cb) Oacc[cb] = 0.f;
  float lrun[4];
#pragma unroll
  for (int r = 0; r < 4; ++r) lrun[r] = 0.f;

  const int rbase = wave * 16 + quad * 4;
  const int kr = tid >> 2, kko = (tid & 3) * 16;   // K staging
  const int vd = tid >> 2, vjo = (tid & 3) * 16;   // V staging (from vT)
  const int po = tid >> 1, pko = (tid & 1) * 32;   // P staging

  bf16x8 kpre[2], vpre[2], ppre[4];
#define LOAD_KVP(JT)                                                          \
  {                                                                           \
    const int j0_ = (JT) * 64;                                                \
    const __bf16* ks_ = Kg + (size_t)(j0_ + kr) * DK_ + kko;                  \
    kpre[0] = *(const bf16x8*)ks_;                                            \
    kpre[1] = *(const bf16x8*)(ks_ + 8);                                      \
    const __bf16* vs_ = Vg + (size_t)vd * T_ + j0_ + vjo;                     \
    vpre[0] = *(const bf16x8*)vs_;                                            \
    vpre[1] = *(const bf16x8*)(vs_ + 8);                                      \
    int cs_ = T_ - 65 + j0_ - i0;                                             \
    if (cs_ < 0) cs_ += T_;                                                   \
    if (cs_ >= T_) cs_ -= T_;                                                 \
    int prow_ = cs_ + po;                                                     \
    if (prow_ >= T_) prow_ -= T_;                                             \
    const __bf16* ps_ = Pg + (size_t)prow_ * DK_ + pko;                       \
    ppre[0] = *(const bf16x8*)ps_;                                            \
    ppre[1] = *(const bf16x8*)(ps_ + 8);                                      \
    ppre[2] = *(const bf16x8*)(ps_ + 16);                                     \
    ppre[3] = *(const bf16x8*)(ps_ + 24);                                     \
  }

  LOAD_KVP(0)

#pragma unroll 1
  for (int jt = 0; jt < 16; ++jt) {
    const int j0 = jt * 64;
    __syncthreads();  // previous iteration's LDS reads (incl. Rs=Kt) complete
    *(bf16x8*)&Kt[kr * 72 + kko] = kpre[0];
    *(bf16x8*)&Kt[kr * 72 + kko + 8] = kpre[1];
    *(bf16x8*)&Vt[vd * 72 + vjo] = vpre[0];
    *(bf16x8*)&Vt[vd * 72 + vjo + 8] = vpre[1];
    *(bf16x8*)&Pb[po * 72 + pko] = ppre[0];
    *(bf16x8*)&Pb[po * 72 + pko + 8] = ppre[1];
    *(bf16x8*)&Pb[po * 72 + pko + 16] = ppre[2];
    *(bf16x8*)&Pb[po * 72 + pko + 24] = ppre[3];
    __syncthreads();
    if (jt < 15) LOAD_KVP(jt + 1)  // overlaps with compute below

    // ---- content scores S = Qu K^T ----
    f32x4 sA[4];
#pragma unroll
    for (int cb = 0; cb < 4; ++cb) sA[cb] = 0.f;
#pragma unroll
    for (int s = 0; s < 2; ++s)
#pragma unroll
      for (int cb = 0; cb < 4; ++cb) {
        bf16x8 kf = *(const bf16x8*)&Kt[(cb * 16 + l16) * 72 + s * 32 + quad * 8];
        sA[cb] = MFMA16(quA[s], kf, sA[cb]);
      }

    __syncthreads();  // ALL waves' Kt reads done before Rs (=Kt) writes below

    // ---- R band GEMM, pre-shifted store (only needed col-blocks) ----
#pragma unroll
    for (int c = 0; c < 5; ++c) {
      const int cb = 3 - wave + c;
      f32x4 rc = 0.f;
#pragma unroll
      for (int s = 0; s < 2; ++s) {
        bf16x8 pf = *(const bf16x8*)&Pb[(cb * 16 + l16) * 72 + s * 32 + quad * 8];
        rc = MFMA16(qvw[s], pf, rc);
      }
      const int col = cb * 16 + l16;
#pragma unroll
      for (int rr = 0; rr < 4; ++rr) {
        const int dj = col + rbase + rr - 64;
        if (dj >= 0 && dj < 64) Rs[(rbase + rr) * 68 + dj] = (__bf16)rc[rr];
      }
    }
    {  // extra row 64 (q row i0+64), cols 0..63, one cb per wave
      const int cb = wave;
      f32x4 rc = 0.f;
#pragma unroll
      for (int s = 0; s < 2; ++s) {
        bf16x8 pf = *(const bf16x8*)&Pb[(cb * 16 + l16) * 72 + s * 32 + quad * 8];
        rc = MFMA16(qv4[s], pf, rc);
      }
      if (quad == 0) Rs[64 * 68 + cb * 16 + l16] = (__bf16)rc[0];
    }
    __syncthreads();

    // ---- gather shifted pos, no-max softmax, stash P (alias of Pb) ----
    __bf16* Pa = Pb;  // safe: Pb fragment reads done before barrier above
#pragma unroll
    for (int r = 0; r < 4; ++r) {
#pragma unroll
      for (int cb = 0; cb < 4; ++cb) {
        const int di = rbase + r;
        const int dj = cb * 16 + l16;
        const int ji = (j0 + dj) - (i0 + di);
        float pos = 0.f;
        if (ji != 1) pos = (float)Rs[(di + (ji >= 2 ? 1 : 0)) * 68 + dj];
        const float w_ = __expf((sA[cb][r] + pos) * SCALE);
        lrun[r] += w_;
        Pa[di * 68 + dj] = (__bf16)w_;
      }
    }

    // ---- O += Pa @ V (wave-local rows; in-wave LDS ordering suffices) ----
#pragma unroll
    for (int s = 0; s < 2; ++s) {
      bf16x8 ap = *(const bf16x8*)&Pa[(wave * 16 + l16) * 68 + s * 32 + quad * 8];
#pragma unroll
      for (int cb = 0; cb < 4; ++cb) {
        bf16x8 bv = *(const bf16x8*)&Vt[(cb * 16 + l16) * 72 + s * 32 + quad * 8];
        Oacc[cb] = MFMA16(ap, bv, Oacc[cb]);
      }
    }
  }

  // ---- epilogue: reduce l over 16 lanes, normalize, store ctx SWIZZLED ----
  float inv[4];
#pragma unroll
  for (int r = 0; r < 4; ++r) {
    float L = lrun[r];
    L += __shfl_xor(L, 1);
    L += __shfl_xor(L, 2);
    L += __shfl_xor(L, 4);
    L += __shfl_xor(L, 8);
    inv[r] = 1.f / L;
  }
  const int b = bhq >> 3, h = bhq & 7;
#pragma unroll
  for (int cb = 0; cb < 4; ++cb)
#pragma unroll
    for (int r = 0; r < 4; ++r) {
      const int row = i0 + rbase + r;
      const int chunk = cb * 2 + (l16 >> 3);
      const int col = h * DK_ + ((chunk ^ (row & 7)) << 3) + (l16 & 7);
      ctx[((size_t)(b * T_ + row)) * D_ + col] = (__bf16)(Oacc[cb][r] * inv[r]);
    }
}

// ---------------------------------------------------------------------------
extern "C" void kernel_launch(void* const* d_in, const int* in_sizes, int n_in,
                              void* d_out, int out_size, void* d_ws,
                              size_t ws_size, hipStream_t stream) {
  const float* query = (const float*)d_in[0];
  const float* key   = (const float*)d_in[1];
  const float* value = (const float*)d_in[2];
  const float* pos   = (const float*)d_in[3];
  const float* Wq = (const float*)d_in[4];
  const float* bq = (const float*)d_in[5];
  const float* Wk = (const float*)d_in[6];
  const float* bk = (const float*)d_in[7];
  const float* Wv = (const float*)d_in[8];
  const float* bv = (const float*)d_in[9];
  const float* Wp = (const float*)d_in[10];
  const float* ub = (const float*)d_in[11];
  const float* vbias = (const float*)d_in[12];
  const float* Wo = (const float*)d_in[13];
  const float* bo = (const float*)d_in[14];
  float* out = (float*)d_out;

  // ws: Xc[4] (32MB, swizzled) | quB,qvB,kB,pB,vT (40MB, plain) | Wt (2.5MB)
  // ctx (swizzled) aliases Xc[0] (query slice, consumed before attn writes).
  char* ws = (char*)d_ws;
  const size_t ACT = (size_t)8192 * 512 * 2;  // 8 MB
  __bf16* Xc  = (__bf16*)ws;                  // 4 slices
  __bf16* quB = (__bf16*)(ws + 4 * ACT);
  __bf16* qvB = (__bf16*)(ws + 5 * ACT);
  __bf16* kB  = (__bf16*)(ws + 6 * ACT);
  __bf16* pB  = (__bf16*)(ws + 7 * ACT);
  __bf16* vT  = (__bf16*)(ws + 8 * ACT);
  __bf16* Wt  = (__bf16*)(ws + 9 * ACT);      // 5 x 512 KB
  __bf16* ctx = Xc;                           // alias (query slice)

  cvt_x<<<dim3(2048, 4), 256, 0, stream>>>(query, key, value, pos, Xc);
  cvt_w<<<dim3(8, 8, 5), 256, 0, stream>>>(Wq, Wk, Wv, Wp, Wo, Wt);

  gemm_dma<0><<<dim3(64, 4, 4), 256, 0, stream>>>(
      Xc, nullptr, Wt, bq, bk, bv, bo, ub, vbias, quB, qvB, kB, vT, pB,
      nullptr);

  attn_mfma<<<dim3(1024), 256, 0, stream>>>(quB, qvB, kB, vT, pB, ctx);

  gemm_dma<1><<<dim3(64, 4, 1), 256, 0, stream>>>(
      nullptr, ctx, Wt, bq, bk, bv, bo, ub, vbias, quB, qvB, kB, vT, pB,
      out);
}

// Round 4
// 257.536 us; speedup vs baseline: 1.8897x; 1.0782x over previous
//
#include <hip/hip_runtime.h>

#define B_ 8
#define T_ 1024
#define D_ 512
#define H_ 8
#define DK_ 64

typedef __bf16 bf16x8 __attribute__((ext_vector_type(8)));
typedef float f32x4 __attribute__((ext_vector_type(4)));

#define MFMA16(a, b, c) __builtin_amdgcn_mfma_f32_16x16x32_bf16(a, b, c, 0, 0, 0)

__device__ __forceinline__ bf16x8 pack8(float4 a, float4 b) {
  bf16x8 r;
  r[0] = (__bf16)a.x; r[1] = (__bf16)a.y; r[2] = (__bf16)a.z; r[3] = (__bf16)a.w;
  r[4] = (__bf16)b.x; r[5] = (__bf16)b.y; r[6] = (__bf16)b.z; r[7] = (__bf16)b.w;
  return r;
}

// async global->LDS DMA, 16 B per lane; lds base must be wave-uniform.
__device__ __forceinline__ void load_lds16(const void* g, void* l) {
  __builtin_amdgcn_global_load_lds(
      (const __attribute__((address_space(1))) void*)g,
      (__attribute__((address_space(3))) void*)l, 16, 0, 0);
}

// ---------------------------------------------------------------------------
// Prep 1: fp32 -> bf16 convert of the 4 activation inputs, SWIZZLED storage:
// within each 64-elem k-segment, chunk c (8 elem) lands at c ^ (row & 7).
// (Consumed only by the DMA GEMM, which reads raw rows and de-swizzles at
// the LDS fragment read.)
// ---------------------------------------------------------------------------
__global__ __launch_bounds__(256) void cvt_x(const float* __restrict__ q,
                                             const float* __restrict__ k,
                                             const float* __restrict__ v,
                                             const float* __restrict__ p,
                                             __bf16* __restrict__ dst) {
  const float* src = (blockIdx.y == 0) ? q
                   : (blockIdx.y == 1) ? k
                   : (blockIdx.y == 2) ? v : p;
  const size_t e = ((size_t)blockIdx.x * 256 + threadIdx.x) * 8;
  const int row = (int)(e >> 9);
  const int kk = (int)(e & 511);
  const int phys = (kk & ~63) | ((((kk >> 3) & 7) ^ (row & 7)) << 3);
  float4 a = *(const float4*)(src + e);
  float4 b = *(const float4*)(src + e + 4);
  *(bf16x8*)(dst + (size_t)blockIdx.y * 4194304 + (size_t)row * 512 + phys) =
      pack8(a, b);
}

// ---------------------------------------------------------------------------
// Prep 2: convert + transpose the 5 weight matrices to bf16 W^T[n][k],
// swizzled the same way (key = n & 7).
// ---------------------------------------------------------------------------
__global__ __launch_bounds__(256) void cvt_w(const float* __restrict__ w0,
                                             const float* __restrict__ w1,
                                             const float* __restrict__ w2,
                                             const float* __restrict__ w3,
                                             const float* __restrict__ w4,
                                             __bf16* __restrict__ wt) {
  __shared__ float Ts[64][65];
  const float* W = (blockIdx.z == 0) ? w0
                 : (blockIdx.z == 1) ? w1
                 : (blockIdx.z == 2) ? w2
                 : (blockIdx.z == 3) ? w3 : w4;
  const int tid = threadIdx.x;
  const int kt = blockIdx.x * 64, nt = blockIdx.y * 64;
  const int r = tid >> 2, co = (tid & 3) * 16;
#pragma unroll
  for (int q = 0; q < 4; ++q)
    *(float4*)&Ts[r][co + q * 4] =
        *(const float4*)(W + (size_t)(kt + r) * 512 + nt + co + q * 4);
  __syncthreads();
  bf16x8 o0, o1;
#pragma unroll
  for (int q = 0; q < 8; ++q) o0[q] = (__bf16)Ts[co + q][r];
#pragma unroll
  for (int q = 0; q < 8; ++q) o1[q] = (__bf16)Ts[co + 8 + q][r];
  const int key = r & 7;
  __bf16* dst =
      wt + (size_t)blockIdx.z * 262144 + (size_t)(nt + r) * 512 + kt;
  *(bf16x8*)(dst + (((co >> 3) ^ key) << 3)) = o0;
  *(bf16x8*)(dst + ((((co >> 3) + 1) ^ key) << 3)) = o1;
}

// ---------------------------------------------------------------------------
// m97-style DMA GEMM: 128x128 tile, BK=64, 256 thr, wave = 64x64 quadrant.
// A and B staged via global_load_lds(16) into unpadded swizzled LDS tiles;
// fragment reads XOR the chunk index with (l16 & 7) -> uniform bank spread.
// PHASE 0 (grid.z = 0..3): A = Xc[z], scatter epilogues
//   z0 -> quB/qvB (+bq+u / +v)  PLAIN (attn reads as register fragments)
//   z1 -> kB (+bk)              SWIZZLED rows (key tt&7)  -> attn K-DMA
//   z2 -> v -> LDS-transpose -> vT [B,H,DK,T], 64-col segs SWIZZLED (key d&7)
//   z3 -> pB                    SWIZZLED rows (key tt&7)  -> attn P-DMA
// PHASE 1: A = ctx (swizzled, written by attn), out fp32 row-major (+bo).
// ---------------------------------------------------------------------------
template <int PHASE>
__global__ __launch_bounds__(256, 4) void gemm_dma(
    const __bf16* __restrict__ Xc, const __bf16* __restrict__ ctxA,
    const __bf16* __restrict__ Wt, const float* __restrict__ bq,
    const float* __restrict__ bk, const float* __restrict__ bv,
    const float* __restrict__ bo, const float* __restrict__ u,
    const float* __restrict__ v, __bf16* __restrict__ quB,
    __bf16* __restrict__ qvB, __bf16* __restrict__ kB,
    __bf16* __restrict__ vT, __bf16* __restrict__ pB,
    float* __restrict__ out) {
  __shared__ __bf16 smem[17408];  // As[8192] | Bs[8192]; epilogue: [128][136]
  __bf16* As = smem;
  __bf16* Bs = smem + 8192;
  const int tid = threadIdx.x;
  const int z = blockIdx.z;
  const int wave = tid >> 6, lane = tid & 63, l16 = lane & 15, quad = lane >> 4;
  const int wm = wave & 1, wn = wave >> 1;
  const int m0 = blockIdx.x * 128, n0 = blockIdx.y * 128;

  const __bf16* Ag = PHASE ? ctxA : Xc + (size_t)z * (8192 * 512);
  const __bf16* Bg = Wt + (size_t)(PHASE ? 4 : z) * (512 * 512);

  const int drow = tid >> 3, dch = (tid & 7) * 8;  // DMA lane mapping
  char* ldsA = (char*)As + (tid & 192) * 16;       // wave-uniform base
  char* ldsB = (char*)Bs + (tid & 192) * 16;
  const int keyc = l16 & 7;                        // frag de-swizzle key

  f32x4 acc[4][4];
#pragma unroll
  for (int rb = 0; rb < 4; ++rb)
#pragma unroll
    for (int cb = 0; cb < 4; ++cb) acc[rb][cb] = 0.f;

#pragma unroll 1
  for (int k0 = 0; k0 < 512; k0 += 64) {
    __syncthreads();  // WAR: previous iteration's fragment reads done
#pragma unroll
    for (int c4 = 0; c4 < 4; ++c4) {
      load_lds16(Ag + (size_t)(m0 + c4 * 32 + drow) * 512 + k0 + dch,
                 ldsA + c4 * 4096);
      load_lds16(Bg + (size_t)(n0 + c4 * 32 + drow) * 512 + k0 + dch,
                 ldsB + c4 * 4096);
    }
    __syncthreads();  // DMA drained (vmcnt) before fragment reads
#pragma unroll
    for (int s = 0; s < 2; ++s) {
      const int ph = ((s * 4 + quad) ^ keyc) << 3;
      bf16x8 afr[4], bfr[4];
#pragma unroll
      for (int rb = 0; rb < 4; ++rb)
        afr[rb] = *(const bf16x8*)&As[(wm * 64 + rb * 16 + l16) * 64 + ph];
#pragma unroll
      for (int cb = 0; cb < 4; ++cb)
        bfr[cb] = *(const bf16x8*)&Bs[(wn * 64 + cb * 16 + l16) * 64 + ph];
#pragma unroll
      for (int rb = 0; rb < 4; ++rb)
#pragma unroll
        for (int cb = 0; cb < 4; ++cb)
          acc[rb][cb] = MFMA16(afr[rb], bfr[cb], acc[rb][cb]);
    }
  }

  if (PHASE == 1) {
#pragma unroll
    for (int rb = 0; rb < 4; ++rb)
#pragma unroll
      for (int cb = 0; cb < 4; ++cb) {
        const int col = n0 + wn * 64 + cb * 16 + l16;
        const float bb = bo[col];
#pragma unroll
        for (int r = 0; r < 4; ++r) {
          const int row = m0 + wm * 64 + rb * 16 + quad * 4 + r;
          out[(size_t)row * 512 + col] = acc[rb][cb][r] + bb;
        }
      }
    return;
  }

  if (z == 2) {  // value: bias, transpose in LDS, write vT swizzled segs
    __syncthreads();
    __bf16* Tt = smem;  // [128][136]
#pragma unroll
    for (int rb = 0; rb < 4; ++rb)
#pragma unroll
      for (int cb = 0; cb < 4; ++cb) {
        const int cl = wn * 64 + cb * 16 + l16;
        const float bb = bv[n0 + cl];
#pragma unroll
        for (int r = 0; r < 4; ++r) {
          const int rl = wm * 64 + rb * 16 + quad * 4 + r;
          Tt[cl * 136 + rl] = (__bf16)(acc[rb][cb][r] + bb);
        }
      }
    __syncthreads();
    const int r2 = tid >> 1, ch = (tid & 1) * 64;
    const int hh = (n0 + r2) >> 6, dkk = (n0 + r2) & 63;
    const int bI = m0 >> 10, t0 = m0 & 1023;
    __bf16* dst = vT + (((size_t)(bI * H_ + hh)) * DK_ + dkk) * T_ + t0 + ch;
    const int vkey = dkk & 7;  // chunk swizzle within each 64-col segment
#pragma unroll
    for (int q = 0; q < 8; ++q)
      *(bf16x8*)(dst + ((q ^ vkey) * 8)) = *(const bf16x8*)&Tt[r2 * 136 + ch + q * 8];
    return;
  }

#pragma unroll
  for (int rb = 0; rb < 4; ++rb)
#pragma unroll
    for (int cb = 0; cb < 4; ++cb) {
      const int col = n0 + wn * 64 + cb * 16 + l16;
      const float bb = (z == 0) ? bq[col] : (z == 1) ? bk[col] : 0.f;
      const float uu = (z == 0) ? u[col] : 0.f;
      const float vv = (z == 0) ? v[col] : 0.f;
#pragma unroll
      for (int r = 0; r < 4; ++r) {
        const int row = m0 + wm * 64 + rb * 16 + quad * 4 + r;
        const float val = acc[rb][cb][r] + bb;
        const int bI = row >> 10, tt = row & 1023;
        const int hh = col >> 6, dk = col & 63;
        // kB/pB rows stored swizzled (key = tt&7) for attn's linear DMA.
        const int dks = (z == 0)
            ? dk
            : ((dk & 7) | ((((dk >> 3) ^ tt) & 7) << 3));
        const size_t idx = (((size_t)(bI * H_ + hh)) * T_ + tt) * DK_ + dks;
        if (z == 0) {
          quB[idx] = (__bf16)(val + uu);
          qvB[idx] = (__bf16)(val + vv);
        } else if (z == 1) {
          kB[idx] = (__bf16)val;
        } else {
          pB[idx] = (__bf16)val;
        }
      }
    }
}

// ---------------------------------------------------------------------------
// Fused MFMA attention — Round-4: register-total fix via DMA staging.
// Evidence r0-r3: occupancy is gated by the unified VGPR+AGPR total per wave
// (HW quantum halves waves at 64/128/256 regs): bound-4 kernels (128 total)
// ran 4 blocks/CU (occ 45%), bound-3 (84 arch + ~64 acc = ~148) ran 2
// (occ 25%). r1/r2 spilled because prefetch state pushed demand past 128.
// Fix: stage K, V, P via global_load_lds (no VGPR data path at all; the
// 32 regs of kpre/vpre/ppre vanish). Global kB/vT/pB are PRE-SWIZZLED
// (chunk ^ row&7) so the DMA is a verbatim linear copy and fragment reads
// de-swizzle with XOR — same proven pattern as gemm_dma.
//   LDS: A[Kt 64x64 | Rs 66x68] 8976 + Vt 64x64 8192 + Pb 128x64 16384
//        = 33552 B; Pa aliases Pb rows 0..63 (own key di&7).
//   P de-swizzle key = (l16+7)&7: band slot row b holds global row cs+b,
//   cs ≡ 63 (mod 64)  =>  key = (b-1)&7.
//   Band phase rewrites every Rs entry each iter (verified coverage), so
//   Rs-over-Kt aliasing never reads stale data.
// __launch_bounds__(256,4): demand ~124 total -> no spill (watch WRITE_SIZE).
// ctx written SWIZZLED (key row&7) for the DMA out-GEMM.
// ---------------------------------------------------------------------------
__global__ __launch_bounds__(256, 4) void attn_mfma(
    const __bf16* __restrict__ qu, const __bf16* __restrict__ qv,
    const __bf16* __restrict__ kbuf, const __bf16* __restrict__ vT,
    const __bf16* __restrict__ pbuf, __bf16* __restrict__ ctx) {
  constexpr float SCALE = 0.044194173824159216f;  // 1/sqrt(512) (d_model)
  __shared__ __bf16 smemA[4488];  // Kt [64][64]; after QK^T: Rs [66][68]
  __shared__ __bf16 Vt[4096];     // V^T tile [64][64] (chunk ^ d&7)
  __shared__ __bf16 Pb[8192];     // P band [128][64] (chunk ^ (row-1)&7)
  __bf16* Kt = smemA;
  __bf16* Rs = smemA;
  __bf16* Pa = Pb;  // P weights [64][64] (chunk ^ di&7), alias band rows 0..63

  const int tid = threadIdx.x;
  const int wave = tid >> 6, lane = tid & 63, l16 = lane & 15, quad = lane >> 4;
  // XCD swizzle: g&7 = XCD slot; 8 whole (b,h) per XCD, 16 i-tiles contiguous.
  const int g = blockIdx.x;
  const int bhq = (g & 7) * 8 + (g >> 7);
  const int i0 = ((g >> 3) & 15) * 64;
  const size_t bh = (size_t)bhq * T_ * DK_;
  const __bf16* QU = qu + bh;
  const __bf16* QV = qv + bh;
  const __bf16* Kg = kbuf + bh;
  const __bf16* Vg = vT + bh;  // [DK][T]
  const __bf16* Pg = pbuf + bh;

  // A-fragments (pre-biased) held all kernel.
  bf16x8 quA[2], qvw[2], qv4[2];
  {
    const int rw = i0 + wave * 16 + l16;
    const int r4g = i0 + 64 + l16;
    const int r4 = (r4g < T_) ? r4g : T_ - 1;
#pragma unroll
    for (int s = 0; s < 2; ++s) {
      const int ko = s * 32 + quad * 8;
      quA[s] = *(const bf16x8*)&QU[(size_t)rw * DK_ + ko];
      qvw[s] = *(const bf16x8*)&QV[(size_t)rw * DK_ + ko];
      qv4[s] = *(const bf16x8*)&QV[(size_t)r4 * DK_ + ko];
    }
  }

  f32x4 Oacc[4];
#pragma unroll
  for (int cb = 0; cb < 4; ++cb) Oacc[cb] = 0.f;
  float lrun[4];
#pragma unroll
  for (int r = 0; r < 4; ++r) lrun[r] = 0.f;

  const int rbase = wave * 16 + quad * 4;
  const int keyr = l16 & 7;            // K/V/Pa de-swizzle key
  const int keyp = (l16 + 7) & 7;      // P band de-swizzle key (row-1 mod 8)
  const int drow = tid >> 3;           // DMA: row within 32-row group
  const int dch = (tid & 7) * 8;       // DMA: elem offset within row
  char* ldsK = (char*)Kt + (tid & 192) * 16;  // wave-uniform bases
  char* ldsV = (char*)Vt + (tid & 192) * 16;
  char* ldsP = (char*)Pb + (tid & 192) * 16;

#pragma unroll 1
  for (int jt = 0; jt < 16; ++jt) {
    const int j0 = jt * 64;
    int cs = T_ - 65 + j0 - i0;
    if (cs < 0) cs += T_;
    if (cs >= T_) cs -= T_;

    __syncthreads();  // previous iteration's LDS reads complete
    // ---- DMA staging: K (8KB), V (8KB), P band (16KB); verbatim copies of
    // pre-swizzled global rows into linear LDS. ----
    load_lds16(Kg + (size_t)(j0 + drow) * 64 + dch, ldsK);
    load_lds16(Kg + (size_t)(j0 + 32 + drow) * 64 + dch, ldsK + 4096);
    load_lds16(Vg + (size_t)drow * T_ + j0 + dch, ldsV);
    load_lds16(Vg + (size_t)(32 + drow) * T_ + j0 + dch, ldsV + 4096);
#pragma unroll
    for (int c = 0; c < 4; ++c) {
      int prow = cs + c * 32 + drow;
      if (prow >= T_) prow -= T_;
      load_lds16(Pg + (size_t)prow * 64 + dch, ldsP + c * 4096);
    }
    __syncthreads();  // DMA drained (vmcnt) before fragment reads

    // ---- content scores S = Qu K^T ----
    f32x4 sA[4];
#pragma unroll
    for (int cb = 0; cb < 4; ++cb) sA[cb] = 0.f;
#pragma unroll
    for (int s = 0; s < 2; ++s)
#pragma unroll
      for (int cb = 0; cb < 4; ++cb) {
        bf16x8 kf = *(const bf16x8*)&Kt[(cb * 16 + l16) * 64 +
                                        (((s * 4 + quad) ^ keyr) << 3)];
        sA[cb] = MFMA16(quA[s], kf, sA[cb]);
      }

    __syncthreads();  // ALL waves' Kt reads done before Rs (=Kt) writes below

    // ---- R band GEMM, pre-shifted store (only needed col-blocks) ----
#pragma unroll
    for (int c = 0; c < 5; ++c) {
      const int cb = 3 - wave + c;
      f32x4 rc = 0.f;
#pragma unroll
      for (int s = 0; s < 2; ++s) {
        bf16x8 pf = *(const bf16x8*)&Pb[(cb * 16 + l16) * 64 +
                                        (((s * 4 + quad) ^ keyp) << 3)];
        rc = MFMA16(qvw[s], pf, rc);
      }
      const int col = cb * 16 + l16;
#pragma unroll
      for (int rr = 0; rr < 4; ++rr) {
        const int dj = col + rbase + rr - 64;
        if (dj >= 0 && dj < 64) Rs[(rbase + rr) * 68 + dj] = (__bf16)rc[rr];
      }
    }
    {  // extra row 64 (q row i0+64), cols 0..63, one cb per wave
      const int cb = wave;
      f32x4 rc = 0.f;
#pragma unroll
      for (int s = 0; s < 2; ++s) {
        bf16x8 pf = *(const bf16x8*)&Pb[(cb * 16 + l16) * 64 +
                                        (((s * 4 + quad) ^ keyp) << 3)];
        rc = MFMA16(qv4[s], pf, rc);
      }
      if (quad == 0) Rs[64 * 68 + cb * 16 + l16] = (__bf16)rc[0];
    }
    __syncthreads();

    // ---- gather shifted pos, no-max softmax, stash P (swizzled, alias Pb) --
#pragma unroll
    for (int r = 0; r < 4; ++r) {
#pragma unroll
      for (int cb = 0; cb < 4; ++cb) {
        const int di = rbase + r;
        const int dj = cb * 16 + l16;
        const int ji = (j0 + dj) - (i0 + di);
        float pos = 0.f;
        if (ji != 1) pos = (float)Rs[(di + (ji >= 2 ? 1 : 0)) * 68 + dj];
        const float w_ = __expf((sA[cb][r] + pos) * SCALE);
        lrun[r] += w_;
        Pa[di * 64 + (dj & 7) + ((((dj >> 3) ^ di) & 7) << 3)] = (__bf16)w_;
      }
    }

    // ---- O += Pa @ V (wave-local rows; in-wave LDS ordering suffices) ----
#pragma unroll
    for (int s = 0; s < 2; ++s) {
      bf16x8 ap = *(const bf16x8*)&Pa[(wave * 16 + l16) * 64 +
                                      (((s * 4 + quad) ^ keyr) << 3)];
#pragma unroll
      for (int cb = 0; cb < 4; ++cb) {
        bf16x8 bv = *(const bf16x8*)&Vt[(cb * 16 + l16) * 64 +
                                        (((s * 4 + quad) ^ keyr) << 3)];
        Oacc[cb] = MFMA16(ap, bv, Oacc[cb]);
      }
    }
  }

  // ---- epilogue: reduce l over 16 lanes, normalize, store ctx SWIZZLED ----
  float inv[4];
#pragma unroll
  for (int r = 0; r < 4; ++r) {
    float L = lrun[r];
    L += __shfl_xor(L, 1);
    L += __shfl_xor(L, 2);
    L += __shfl_xor(L, 4);
    L += __shfl_xor(L, 8);
    inv[r] = 1.f / L;
  }
  const int b = bhq >> 3, h = bhq & 7;
#pragma unroll
  for (int cb = 0; cb < 4; ++cb)
#pragma unroll
    for (int r = 0; r < 4; ++r) {
      const int row = i0 + rbase + r;
      const int chunk = cb * 2 + (l16 >> 3);
      const int col = h * DK_ + ((chunk ^ (row & 7)) << 3) + (l16 & 7);
      ctx[((size_t)(b * T_ + row)) * D_ + col] = (__bf16)(Oacc[cb][r] * inv[r]);
    }
}

// ---------------------------------------------------------------------------
extern "C" void kernel_launch(void* const* d_in, const int* in_sizes, int n_in,
                              void* d_out, int out_size, void* d_ws,
                              size_t ws_size, hipStream_t stream) {
  const float* query = (const float*)d_in[0];
  const float* key   = (const float*)d_in[1];
  const float* value = (const float*)d_in[2];
  const float* pos   = (const float*)d_in[3];
  const float* Wq = (const float*)d_in[4];
  const float* bq = (const float*)d_in[5];
  const float* Wk = (const float*)d_in[6];
  const float* bk = (const float*)d_in[7];
  const float* Wv = (const float*)d_in[8];
  const float* bv = (const float*)d_in[9];
  const float* Wp = (const float*)d_in[10];
  const float* ub = (const float*)d_in[11];
  const float* vbias = (const float*)d_in[12];
  const float* Wo = (const float*)d_in[13];
  const float* bo = (const float*)d_in[14];
  float* out = (float*)d_out;

  // ws: Xc[4] (32MB, swizzled) | quB,qvB,kB,pB,vT (40MB) | Wt (2.5MB)
  // ctx (swizzled) aliases Xc[0] (query slice, consumed before attn writes).
  char* ws = (char*)d_ws;
  const size_t ACT = (size_t)8192 * 512 * 2;  // 8 MB
  __bf16* Xc  = (__bf16*)ws;                  // 4 slices
  __bf16* quB = (__bf16*)(ws + 4 * ACT);
  __bf16* qvB = (__bf16*)(ws + 5 * ACT);
  __bf16* kB  = (__bf16*)(ws + 6 * ACT);
  __bf16* pB  = (__bf16*)(ws + 7 * ACT);
  __bf16* vT  = (__bf16*)(ws + 8 * ACT);
  __bf16* Wt  = (__bf16*)(ws + 9 * ACT);      // 5 x 512 KB
  __bf16* ctx = Xc;                           // alias (query slice)

  cvt_x<<<dim3(2048, 4), 256, 0, stream>>>(query, key, value, pos, Xc);
  cvt_w<<<dim3(8, 8, 5), 256, 0, stream>>>(Wq, Wk, Wv, Wp, Wo, Wt);

  gemm_dma<0><<<dim3(64, 4, 4), 256, 0, stream>>>(
      Xc, nullptr, Wt, bq, bk, bv, bo, ub, vbias, quB, qvB, kB, vT, pB,
      nullptr);

  attn_mfma<<<dim3(1024), 256, 0, stream>>>(quB, qvB, kB, vT, pB, ctx);

  gemm_dma<1><<<dim3(64, 4, 1), 256, 0, stream>>>(
      nullptr, ctx, Wt, bq, bk, bv, bo, ub, vbias, quB, qvB, kB, vT, pB,
      out);
}

// Round 5
// 247.070 us; speedup vs baseline: 1.9698x; 1.0424x over previous
//
#include <hip/hip_runtime.h>

#define B_ 8
#define T_ 1024
#define D_ 512
#define H_ 8
#define DK_ 64

typedef __bf16 bf16x8 __attribute__((ext_vector_type(8)));
typedef float f32x4 __attribute__((ext_vector_type(4)));

#define MFMA16(a, b, c) __builtin_amdgcn_mfma_f32_16x16x32_bf16(a, b, c, 0, 0, 0)

__device__ __forceinline__ bf16x8 pack8(float4 a, float4 b) {
  bf16x8 r;
  r[0] = (__bf16)a.x; r[1] = (__bf16)a.y; r[2] = (__bf16)a.z; r[3] = (__bf16)a.w;
  r[4] = (__bf16)b.x; r[5] = (__bf16)b.y; r[6] = (__bf16)b.z; r[7] = (__bf16)b.w;
  return r;
}

// async global->LDS DMA, 16 B per lane; lds base must be wave-uniform.
__device__ __forceinline__ void load_lds16(const void* g, void* l) {
  __builtin_amdgcn_global_load_lds(
      (const __attribute__((address_space(1))) void*)g,
      (__attribute__((address_space(3))) void*)l, 16, 0, 0);
}

// ---------------------------------------------------------------------------
// Prep: convert + transpose the 5 weight matrices to bf16 W^T[n][k],
// swizzled (key = n & 7) for the GEMM's linear B-DMA + XOR fragment reads.
// ---------------------------------------------------------------------------
__global__ __launch_bounds__(256) void cvt_w(const float* __restrict__ w0,
                                             const float* __restrict__ w1,
                                             const float* __restrict__ w2,
                                             const float* __restrict__ w3,
                                             const float* __restrict__ w4,
                                             __bf16* __restrict__ wt) {
  __shared__ float Ts[64][65];
  const float* W = (blockIdx.z == 0) ? w0
                 : (blockIdx.z == 1) ? w1
                 : (blockIdx.z == 2) ? w2
                 : (blockIdx.z == 3) ? w3 : w4;
  const int tid = threadIdx.x;
  const int kt = blockIdx.x * 64, nt = blockIdx.y * 64;
  const int r = tid >> 2, co = (tid & 3) * 16;
#pragma unroll
  for (int q = 0; q < 4; ++q)
    *(float4*)&Ts[r][co + q * 4] =
        *(const float4*)(W + (size_t)(kt + r) * 512 + nt + co + q * 4);
  __syncthreads();
  bf16x8 o0, o1;
#pragma unroll
  for (int q = 0; q < 8; ++q) o0[q] = (__bf16)Ts[co + q][r];
#pragma unroll
  for (int q = 0; q < 8; ++q) o1[q] = (__bf16)Ts[co + 8 + q][r];
  const int key = r & 7;
  __bf16* dst =
      wt + (size_t)blockIdx.z * 262144 + (size_t)(nt + r) * 512 + kt;
  *(bf16x8*)(dst + (((co >> 3) ^ key) << 3)) = o0;
  *(bf16x8*)(dst + ((((co >> 3) + 1) ^ key) << 3)) = o1;
}

// ---------------------------------------------------------------------------
// DMA GEMM: 128x128 tile, BK=64, 256 thr, wave = 64x64 quadrant.
// B staged via global_load_lds(16) from pre-swizzled Wt (de-swizzle at frag
// read). PHASE 0: A = fp32 activation (q/k/v/p), REG-STAGED: float4x2 ->
// bf16x8 -> swizzled ds_write_b128 (cvt_x kernel deleted this round).
// PHASE 1: A = ctx (bf16, swizzled by attn) via DMA.
// Epilogues (PHASE 0): all outputs staged through LDS [128][136] and written
// as 128-B contiguous row-chunks (wave = 8 KB coalesced):
//   z0 -> quB (+bq+u) and qvB (+bq+v), plain rows
//   z1 -> kB (+bk), rows chunk-swizzled (key tt&7) for attn's linear K-DMA
//   z2 -> vT [B,H,DK,T] via LDS transpose, 64-col segs swizzled (key d&7)
//   z3 -> pB, rows chunk-swizzled (key tt&7)
// PHASE 1: out fp32 row-major (+bo).
// ---------------------------------------------------------------------------
template <int PHASE>
__global__ __launch_bounds__(256, 4) void gemm_dma(
    const float* __restrict__ qf, const float* __restrict__ kf,
    const float* __restrict__ vf, const float* __restrict__ pf,
    const __bf16* __restrict__ ctxA, const __bf16* __restrict__ Wt,
    const float* __restrict__ bq, const float* __restrict__ bk,
    const float* __restrict__ bv, const float* __restrict__ bo,
    const float* __restrict__ ub, const float* __restrict__ vb,
    __bf16* __restrict__ quB, __bf16* __restrict__ qvB,
    __bf16* __restrict__ kB, __bf16* __restrict__ vT,
    __bf16* __restrict__ pB, float* __restrict__ out) {
  __shared__ __bf16 smem[17408];  // As[8192] | Bs[8192]; epilogue: [128][136]
  __bf16* As = smem;
  __bf16* Bs = smem + 8192;
  const int tid = threadIdx.x;
  const int z = blockIdx.z;
  const int wave = tid >> 6, lane = tid & 63, l16 = lane & 15, quad = lane >> 4;
  const int wm = wave & 1, wn = wave >> 1;
  const int m0 = blockIdx.x * 128, n0 = blockIdx.y * 128;

  const float* Af = (z == 0) ? qf : (z == 1) ? kf : (z == 2) ? vf : pf;
  const __bf16* Bg = Wt + (size_t)(PHASE ? 4 : z) * (512 * 512);

  const int drow = tid >> 3, dch = (tid & 7) * 8;  // staging lane mapping
  char* ldsA = (char*)As + (tid & 192) * 16;       // wave-uniform base
  char* ldsB = (char*)Bs + (tid & 192) * 16;
  const int keyc = l16 & 7;                        // frag de-swizzle key

  f32x4 acc[4][4];
#pragma unroll
  for (int rb = 0; rb < 4; ++rb)
#pragma unroll
    for (int cb = 0; cb < 4; ++cb) acc[rb][cb] = 0.f;

#pragma unroll 1
  for (int k0 = 0; k0 < 512; k0 += 64) {
    __syncthreads();  // WAR: previous iteration's fragment reads done
#pragma unroll
    for (int c4 = 0; c4 < 4; ++c4)
      load_lds16(Bg + (size_t)(n0 + c4 * 32 + drow) * 512 + k0 + dch,
                 ldsB + c4 * 4096);
    if (PHASE == 1) {
#pragma unroll
      for (int c4 = 0; c4 < 4; ++c4)
        load_lds16(ctxA + (size_t)(m0 + c4 * 32 + drow) * 512 + k0 + dch,
                   ldsA + c4 * 4096);
    } else {
      // reg-staged A: fp32 -> bf16, swizzled LDS write (key row&7)
#pragma unroll
      for (int c4 = 0; c4 < 4; ++c4) {
        const int row = c4 * 32 + drow;
        const float* s = Af + (size_t)(m0 + row) * 512 + k0 + dch;
        float4 a0 = *(const float4*)s;
        float4 a1 = *(const float4*)(s + 4);
        *(bf16x8*)&As[row * 64 + ((((dch >> 3) ^ row) & 7) << 3)] =
            pack8(a0, a1);
      }
    }
    __syncthreads();  // B-DMA drained + A ds_writes visible
#pragma unroll
    for (int s = 0; s < 2; ++s) {
      const int ph = ((s * 4 + quad) ^ keyc) << 3;
      bf16x8 afr[4], bfr[4];
#pragma unroll
      for (int rb = 0; rb < 4; ++rb)
        afr[rb] = *(const bf16x8*)&As[(wm * 64 + rb * 16 + l16) * 64 + ph];
#pragma unroll
      for (int cb = 0; cb < 4; ++cb)
        bfr[cb] = *(const bf16x8*)&Bs[(wn * 64 + cb * 16 + l16) * 64 + ph];
#pragma unroll
      for (int rb = 0; rb < 4; ++rb)
#pragma unroll
        for (int cb = 0; cb < 4; ++cb)
          acc[rb][cb] = MFMA16(afr[rb], bfr[cb], acc[rb][cb]);
    }
  }

  if (PHASE == 1) {
#pragma unroll
    for (int rb = 0; rb < 4; ++rb)
#pragma unroll
      for (int cb = 0; cb < 4; ++cb) {
        const int col = n0 + wn * 64 + cb * 16 + l16;
        const float bb = bo[col];
#pragma unroll
        for (int r = 0; r < 4; ++r) {
          const int row = m0 + wm * 64 + rb * 16 + quad * 4 + r;
          out[(size_t)row * 512 + col] = acc[rb][cb][r] + bb;
        }
      }
    return;
  }

  __syncthreads();  // all fragment reads done; smem reusable

  if (z == 2) {  // value: bias, transpose in LDS, write vT swizzled segs
    __bf16* Tt = smem;  // [128][136]
#pragma unroll
    for (int rb = 0; rb < 4; ++rb)
#pragma unroll
      for (int cb = 0; cb < 4; ++cb) {
        const int cl = wn * 64 + cb * 16 + l16;
        const float bb = bv[n0 + cl];
#pragma unroll
        for (int r = 0; r < 4; ++r) {
          const int rl = wm * 64 + rb * 16 + quad * 4 + r;
          Tt[cl * 136 + rl] = (__bf16)(acc[rb][cb][r] + bb);
        }
      }
    __syncthreads();
    const int r2 = tid >> 1, ch = (tid & 1) * 64;
    const int hh = (n0 + r2) >> 6, dkk = (n0 + r2) & 63;
    const int bI = m0 >> 10, t0 = m0 & 1023;
    __bf16* dst = vT + (((size_t)(bI * H_ + hh)) * DK_ + dkk) * T_ + t0 + ch;
    const int vkey = dkk & 7;  // chunk swizzle within each 64-col segment
#pragma unroll
    for (int q = 0; q < 8; ++q)
      *(bf16x8*)(dst + ((q ^ vkey) * 8)) =
          *(const bf16x8*)&Tt[r2 * 136 + ch + q * 8];
    return;
  }

  // z0/z1/z3: LDS-staged vectorized epilogue (coalesced 128-B row chunks).
  __bf16* Tt = smem;  // [128][136]
  const int trow = tid & 127, hs = tid >> 7;
  const int bI = m0 >> 10, tt = (m0 & 1023) + trow;
  const int hh = (n0 >> 6) + hs;
  const size_t obase = (((size_t)(bI * H_ + hh)) * T_ + tt) * DK_;
  const int npass = (z == 0) ? 2 : 1;
#pragma unroll 1
  for (int pass = 0; pass < npass; ++pass) {
#pragma unroll
    for (int rb = 0; rb < 4; ++rb)
#pragma unroll
      for (int cb = 0; cb < 4; ++cb) {
        const int cl = wn * 64 + cb * 16 + l16;
        const int col = n0 + cl;
        const float b0 = (z == 0) ? bq[col] : (z == 1) ? bk[col] : 0.f;
        const float b1 = (z == 0) ? (pass ? vb[col] : ub[col]) : 0.f;
#pragma unroll
        for (int r = 0; r < 4; ++r) {
          const int rl = wm * 64 + rb * 16 + quad * 4 + r;
          Tt[rl * 136 + cl] = (__bf16)((acc[rb][cb][r] + b0) + b1);
        }
      }
    __syncthreads();
    __bf16* dst = ((z == 0) ? (pass ? qvB : quB) : (z == 1) ? kB : pB) + obase;
#pragma unroll
    for (int qd = 0; qd < 8; ++qd) {
      const int c = (z == 0) ? qd : (qd ^ (tt & 7));  // kB/pB chunk swizzle
      *(bf16x8*)(dst + c * 8) =
          *(const bf16x8*)&Tt[trow * 136 + hs * 64 + qd * 8];
    }
    if (pass + 1 < npass) __syncthreads();
  }
}

// ---------------------------------------------------------------------------
// Fused MFMA attention — r4 structure (DMA staging, pre-swizzled global,
// VGPR total <=128 -> 4 blocks/CU) + r5 split-drain:
// issue K,K | sched_barrier | V,V,P*4, wait vmcnt(6) + raw s_barrier -> QK^T
// runs while the 24 KB of V+P DMA is still in flight; vmcnt(0) + barrier
// before the band phase (which already existed as the Rs-over-Kt WAR guard).
// Each wave's 2 oldest outstanding loads are its own K -> vmcnt(6) at the
// barrier guarantees all waves' K complete.
// ---------------------------------------------------------------------------
__global__ __launch_bounds__(256, 4) void attn_mfma(
    const __bf16* __restrict__ qu, const __bf16* __restrict__ qv,
    const __bf16* __restrict__ kbuf, const __bf16* __restrict__ vT,
    const __bf16* __restrict__ pbuf, __bf16* __restrict__ ctx) {
  constexpr float SCALE = 0.044194173824159216f;  // 1/sqrt(512) (d_model)
  __shared__ __bf16 smemA[4488];  // Kt [64][64]; after QK^T: Rs [66][68]
  __shared__ __bf16 Vt[4096];     // V^T tile [64][64] (chunk ^ d&7)
  __shared__ __bf16 Pb[8192];     // P band [128][64] (chunk ^ (row-1)&7)
  __bf16* Kt = smemA;
  __bf16* Rs = smemA;
  __bf16* Pa = Pb;  // P weights [64][64] (chunk ^ di&7), alias band rows 0..63

  const int tid = threadIdx.x;
  const int wave = tid >> 6, lane = tid & 63, l16 = lane & 15, quad = lane >> 4;
  // XCD swizzle: g&7 = XCD slot; 8 whole (b,h) per XCD, 16 i-tiles contiguous.
  const int g = blockIdx.x;
  const int bhq = (g & 7) * 8 + (g >> 7);
  const int i0 = ((g >> 3) & 15) * 64;
  const size_t bh = (size_t)bhq * T_ * DK_;
  const __bf16* QU = qu + bh;
  const __bf16* QV = qv + bh;
  const __bf16* Kg = kbuf + bh;
  const __bf16* Vg = vT + bh;  // [DK][T]
  const __bf16* Pg = pbuf + bh;

  // A-fragments (pre-biased) held all kernel.
  bf16x8 quA[2], qvw[2], qv4[2];
  {
    const int rw = i0 + wave * 16 + l16;
    const int r4g = i0 + 64 + l16;
    const int r4 = (r4g < T_) ? r4g : T_ - 1;
#pragma unroll
    for (int s = 0; s < 2; ++s) {
      const int ko = s * 32 + quad * 8;
      quA[s] = *(const bf16x8*)&QU[(size_t)rw * DK_ + ko];
      qvw[s] = *(const bf16x8*)&QV[(size_t)rw * DK_ + ko];
      qv4[s] = *(const bf16x8*)&QV[(size_t)r4 * DK_ + ko];
    }
  }

  f32x4 Oacc[4];
#pragma unroll
  for (int cb = 0; cb < 4; ++cb) Oacc[cb] = 0.f;
  float lrun[4];
#pragma unroll
  for (int r = 0; r < 4; ++r) lrun[r] = 0.f;

  const int rbase = wave * 16 + quad * 4;
  const int keyr = l16 & 7;            // K/V/Pa de-swizzle key
  const int keyp = (l16 + 7) & 7;      // P band de-swizzle key (row-1 mod 8)
  const int drow = tid >> 3;           // DMA: row within 32-row group
  const int dch = (tid & 7) * 8;       // DMA: elem offset within row
  char* ldsK = (char*)Kt + (tid & 192) * 16;  // wave-uniform bases
  char* ldsV = (char*)Vt + (tid & 192) * 16;
  char* ldsP = (char*)Pb + (tid & 192) * 16;

#pragma unroll 1
  for (int jt = 0; jt < 16; ++jt) {
    const int j0 = jt * 64;
    int cs = T_ - 65 + j0 - i0;
    if (cs < 0) cs += T_;
    if (cs >= T_) cs -= T_;

    __syncthreads();  // previous iteration's LDS reads complete
    // ---- DMA staging. Issue order is load-bearing: K first (the 2 oldest
    // per wave), so vmcnt(6) below releases QK^T while V+P stay in flight.
    load_lds16(Kg + (size_t)(j0 + drow) * 64 + dch, ldsK);
    load_lds16(Kg + (size_t)(j0 + 32 + drow) * 64 + dch, ldsK + 4096);
    __builtin_amdgcn_sched_barrier(0);  // pin K-issue order
    load_lds16(Vg + (size_t)drow * T_ + j0 + dch, ldsV);
    load_lds16(Vg + (size_t)(32 + drow) * T_ + j0 + dch, ldsV + 4096);
#pragma unroll
    for (int c = 0; c < 4; ++c) {
      int prow = cs + c * 32 + drow;
      if (prow >= T_) prow -= T_;
      load_lds16(Pg + (size_t)prow * 64 + dch, ldsP + c * 4096);
    }
    asm volatile("s_waitcnt vmcnt(6)" ::: "memory");  // K ready
    __builtin_amdgcn_s_barrier();

    // ---- content scores S = Qu K^T (V+P DMA still in flight) ----
    f32x4 sA[4];
#pragma unroll
    for (int cb = 0; cb < 4; ++cb) sA[cb] = 0.f;
#pragma unroll
    for (int s = 0; s < 2; ++s)
#pragma unroll
      for (int cb = 0; cb < 4; ++cb) {
        bf16x8 kf = *(const bf16x8*)&Kt[(cb * 16 + l16) * 64 +
                                        (((s * 4 + quad) ^ keyr) << 3)];
        sA[cb] = MFMA16(quA[s], kf, sA[cb]);
      }

    asm volatile("s_waitcnt vmcnt(0)" ::: "memory");  // V+P ready
    __builtin_amdgcn_s_barrier();  // also: Kt reads done before Rs writes

    // ---- R band GEMM, pre-shifted store (only needed col-blocks) ----
#pragma unroll
    for (int c = 0; c < 5; ++c) {
      const int cb = 3 - wave + c;
      f32x4 rc = 0.f;
#pragma unroll
      for (int s = 0; s < 2; ++s) {
        bf16x8 pf = *(const bf16x8*)&Pb[(cb * 16 + l16) * 64 +
                                        (((s * 4 + quad) ^ keyp) << 3)];
        rc = MFMA16(qvw[s], pf, rc);
      }
      const int col = cb * 16 + l16;
#pragma unroll
      for (int rr = 0; rr < 4; ++rr) {
        const int dj = col + rbase + rr - 64;
        if (dj >= 0 && dj < 64) Rs[(rbase + rr) * 68 + dj] = (__bf16)rc[rr];
      }
    }
    {  // extra row 64 (q row i0+64), cols 0..63, one cb per wave
      const int cb = wave;
      f32x4 rc = 0.f;
#pragma unroll
      for (int s = 0; s < 2; ++s) {
        bf16x8 pf = *(const bf16x8*)&Pb[(cb * 16 + l16) * 64 +
                                        (((s * 4 + quad) ^ keyp) << 3)];
        rc = MFMA16(qv4[s], pf, rc);
      }
      if (quad == 0) Rs[64 * 68 + cb * 16 + l16] = (__bf16)rc[0];
    }
    __syncthreads();

    // ---- gather shifted pos, no-max softmax, stash P (swizzled, alias Pb) --
#pragma unroll
    for (int r = 0; r < 4; ++r) {
#pragma unroll
      for (int cb = 0; cb < 4; ++cb) {
        const int di = rbase + r;
        const int dj = cb * 16 + l16;
        const int ji = (j0 + dj) - (i0 + di);
        float pos = 0.f;
        if (ji != 1) pos = (float)Rs[(di + (ji >= 2 ? 1 : 0)) * 68 + dj];
        const float w_ = __expf((sA[cb][r] + pos) * SCALE);
        lrun[r] += w_;
        Pa[di * 64 + (dj & 7) + ((((dj >> 3) ^ di) & 7) << 3)] = (__bf16)w_;
      }
    }

    // ---- O += Pa @ V (wave-local rows; in-wave LDS ordering suffices) ----
#pragma unroll
    for (int s = 0; s < 2; ++s) {
      bf16x8 ap = *(const bf16x8*)&Pa[(wave * 16 + l16) * 64 +
                                      (((s * 4 + quad) ^ keyr) << 3)];
#pragma unroll
      for (int cb = 0; cb < 4; ++cb) {
        bf16x8 bv = *(const bf16x8*)&Vt[(cb * 16 + l16) * 64 +
                                        (((s * 4 + quad) ^ keyr) << 3)];
        Oacc[cb] = MFMA16(ap, bv, Oacc[cb]);
      }
    }
  }

  // ---- epilogue: reduce l over 16 lanes, normalize, store ctx SWIZZLED ----
  float inv[4];
#pragma unroll
  for (int r = 0; r < 4; ++r) {
    float L = lrun[r];
    L += __shfl_xor(L, 1);
    L += __shfl_xor(L, 2);
    L += __shfl_xor(L, 4);
    L += __shfl_xor(L, 8);
    inv[r] = 1.f / L;
  }
  const int b = bhq >> 3, h = bhq & 7;
#pragma unroll
  for (int cb = 0; cb < 4; ++cb)
#pragma unroll
    for (int r = 0; r < 4; ++r) {
      const int row = i0 + rbase + r;
      const int chunk = cb * 2 + (l16 >> 3);
      const int col = h * DK_ + ((chunk ^ (row & 7)) << 3) + (l16 & 7);
      ctx[((size_t)(b * T_ + row)) * D_ + col] = (__bf16)(Oacc[cb][r] * inv[r]);
    }
}

// ---------------------------------------------------------------------------
extern "C" void kernel_launch(void* const* d_in, const int* in_sizes, int n_in,
                              void* d_out, int out_size, void* d_ws,
                              size_t ws_size, hipStream_t stream) {
  const float* query = (const float*)d_in[0];
  const float* key   = (const float*)d_in[1];
  const float* value = (const float*)d_in[2];
  const float* pos   = (const float*)d_in[3];
  const float* Wq = (const float*)d_in[4];
  const float* bq = (const float*)d_in[5];
  const float* Wk = (const float*)d_in[6];
  const float* bk = (const float*)d_in[7];
  const float* Wv = (const float*)d_in[8];
  const float* bv = (const float*)d_in[9];
  const float* Wp = (const float*)d_in[10];
  const float* ub = (const float*)d_in[11];
  const float* vbias = (const float*)d_in[12];
  const float* Wo = (const float*)d_in[13];
  const float* bo = (const float*)d_in[14];
  float* out = (float*)d_out;

  // ws: quB,qvB,kB,pB,vT,ctx (6 x 8MB) | Wt (2.5MB). cvt_x/Xc deleted:
  // gemm0 reg-stages fp32 A directly.
  char* ws = (char*)d_ws;
  const size_t ACT = (size_t)8192 * 512 * 2;  // 8 MB
  __bf16* quB = (__bf16*)ws;
  __bf16* qvB = (__bf16*)(ws + 1 * ACT);
  __bf16* kB  = (__bf16*)(ws + 2 * ACT);
  __bf16* pB  = (__bf16*)(ws + 3 * ACT);
  __bf16* vT  = (__bf16*)(ws + 4 * ACT);
  __bf16* ctx = (__bf16*)(ws + 5 * ACT);
  __bf16* Wt  = (__bf16*)(ws + 6 * ACT);      // 5 x 512 KB

  cvt_w<<<dim3(8, 8, 5), 256, 0, stream>>>(Wq, Wk, Wv, Wp, Wo, Wt);

  gemm_dma<0><<<dim3(64, 4, 4), 256, 0, stream>>>(
      query, key, value, pos, nullptr, Wt, bq, bk, bv, bo, ub, vbias,
      quB, qvB, kB, vT, pB, nullptr);

  attn_mfma<<<dim3(1024), 256, 0, stream>>>(quB, qvB, kB, vT, pB, ctx);

  gemm_dma<1><<<dim3(64, 4, 1), 256, 0, stream>>>(
      nullptr, nullptr, nullptr, nullptr, ctx, Wt, bq, bk, bv, bo, ub, vbias,
      quB, qvB, kB, vT, pB, out);
}